// Round 1
// baseline (321.389 us; speedup 1.0000x reference)
//
#include <hip/hip_runtime.h>
#include <cstdint>
#include <cstddef>

#define KTOT 25088   // C*P*P = 512*49
#define NBOX 2048    // B*N
#define HID  1024

typedef __bf16 bf16x8 __attribute__((ext_vector_type(8)));
typedef float  f32x4  __attribute__((ext_vector_type(4)));

__device__ __forceinline__ unsigned short f2bf(float f) {
  union { float f; unsigned u; } v; v.f = f;
  unsigned r = v.u + 0x7FFFu + ((v.u >> 16) & 1u);   // RNE
  return (unsigned short)(r >> 16);
}

// image_h/w arrive as 1-element arrays; hedge int32/int64 vs float32 storage.
__device__ __forceinline__ float scalar_f(const void* p) {
  int iv = *(const int*)p;
  if (iv > 0 && iv < (1 << 20)) return (float)iv;
  return *(const float*)p;
}

// ---- kernel 1: mean over T + transpose -> fbhwc (B,14,14,C) f32
__global__ __launch_bounds__(256) void k_meant(const float* __restrict__ feature,
                                               float* __restrict__ fbhwc) {
  int id = blockIdx.x * 256 + threadIdx.x;
  if (id >= 4 * 512 * 196) return;
  int pix = id % 196;
  int c   = (id / 196) & 511;
  int b   = id / (196 * 512);
  const float* p = feature + ((size_t)(b * 512 + c) * 8) * 196 + pix;
  float s = 0.f;
#pragma unroll
  for (int t = 0; t < 8; ++t) s += p[t * 196];
  fbhwc[((size_t)(b * 196 + pix)) * 512 + c] = s * 0.125f;
}

// ---- kernel 2: IoU max/argmax + global any_fg flag
__global__ __launch_bounds__(256) void k_iou(const float* __restrict__ prop,
                                             const float* __restrict__ gtb,
                                             float* __restrict__ max_iou,
                                             int* __restrict__ assign,
                                             int* __restrict__ flag) {
  __shared__ float g[128];
  int gid = blockIdx.x * 256 + threadIdx.x;   // 0..2047, one b per block
  int b = gid >> 9;
  if (threadIdx.x < 128) g[threadIdx.x] = gtb[b * 128 + threadIdx.x];
  __syncthreads();
  float x1 = prop[gid * 4 + 0], y1 = prop[gid * 4 + 1];
  float x2 = prop[gid * 4 + 2], y2 = prop[gid * 4 + 3];
  float aa = (x2 - x1) * (y2 - y1);
  float best = -1e30f; int arg = 0;
  for (int m = 0; m < 32; ++m) {
    float gx1 = g[m*4], gy1 = g[m*4+1], gx2 = g[m*4+2], gy2 = g[m*4+3];
    float iw = fmaxf(fminf(x2, gx2) - fmaxf(x1, gx1), 0.f);
    float ih = fmaxf(fminf(y2, gy2) - fmaxf(y1, gy1), 0.f);
    float inter = iw * ih;
    float ab = (gx2 - gx1) * (gy2 - gy1);
    float iou = inter / (aa + ab - inter + 1e-8f);
    if (iou > best) { best = iou; arg = m; }   // strict > == argmax first-max
  }
  max_iou[gid] = best; assign[gid] = arg;
  if (best >= 0.85f) atomicOr(flag, 1);
}

// ---- kernel 3: W1 (25088x1024 f32, row k=c*49+bin) -> W1T (1024 x 25088 bf16, col k'=bin*512+c)
__global__ __launch_bounds__(256) void k_w1t(const float* __restrict__ W1,
                                             unsigned short* __restrict__ W1T) {
  __shared__ unsigned short tile[32][33];
  int kp0 = blockIdx.x * 32;
  int h0  = blockIdx.y * 32;
  int tj = threadIdx.x & 31;
  int ti = threadIdx.x >> 5;
#pragma unroll
  for (int r = 0; r < 4; ++r) {
    int i = ti + r * 8;
    int kp = kp0 + i;
    int srow = (kp & 511) * 49 + (kp >> 9);     // c*49 + bin
    tile[i][tj] = f2bf(W1[(size_t)srow * 1024 + h0 + tj]);
  }
  __syncthreads();
#pragma unroll
  for (int r = 0; r < 4; ++r) {
    int hi = ti + r * 8;
    W1T[(size_t)(h0 + hi) * KTOT + kp0 + tj] = tile[tj][hi];
  }
}

// ---- kernel 4: ROI-pool -> Apool (2048 x 25088 bf16), row layout k'=bin*512+c
__global__ __launch_bounds__(256) void k_roipool(const float* __restrict__ fbhwc,
                                                 const float* __restrict__ prop,
                                                 const void* ihp, const void* iwp,
                                                 unsigned short* __restrict__ Apool) {
  int n = blockIdx.x;
  int tid = threadIdx.x;
  float sy = 14.f / scalar_f(ihp);
  float sx = 14.f / scalar_f(iwp);
  float bx1 = prop[n*4+0]*sx, by1 = prop[n*4+1]*sy;
  float bx2 = prop[n*4+2]*sx, by2 = prop[n*4+3]*sy;
  const float* fb = fbhwc + (size_t)(n >> 9) * 196 * 512;
  unsigned short* arow = Apool + (size_t)n * KTOT;
  for (int bin = 0; bin < 49; ++bin) {
    int py = bin / 7, px = bin - py * 7;
    float y = by1 + ((py + 0.5f) / 7.f) * (by2 - by1) - 0.5f;
    float x = bx1 + ((px + 0.5f) / 7.f) * (bx2 - bx1) - 0.5f;
    float y0f = floorf(y), x0f = floorf(x);
    float wy = y - y0f, wx = x - x0f;          // fract in [0,1): clip is a no-op
    int y0  = min(max((int)y0f, 0), 13);
    int y1i = min(max((int)y0f + 1, 0), 13);
    int x0  = min(max((int)x0f, 0), 13);
    int x1i = min(max((int)x0f + 1, 0), 13);
    const float* f00 = fb + (y0 * 14 + x0 ) * 512;
    const float* f01 = fb + (y0 * 14 + x1i) * 512;
    const float* f10 = fb + (y1i * 14 + x0 ) * 512;
    const float* f11 = fb + (y1i * 14 + x1i) * 512;
    float w00 = (1.f - wy) * (1.f - wx), w01 = (1.f - wy) * wx;
    float w10 = wy * (1.f - wx),         w11 = wy * wx;
    unsigned short* orow = arow + bin * 512;
    for (int c = tid; c < 512; c += 256) {
      float v = f00[c]*w00 + f01[c]*w01 + f10[c]*w10 + f11[c]*w11;
      orow[c] = f2bf(v);
    }
  }
}

// ---- kernel 5: GEMM1, 128x128 tile, BK=32, split-K=4 -> fp32 partials
__device__ __forceinline__ void gload16(const unsigned short* g, unsigned short* l) {
  __builtin_amdgcn_global_load_lds(
      (const __attribute__((address_space(1))) unsigned int*)g,
      (__attribute__((address_space(3))) unsigned int*)l, 16, 0, 0);
}

__global__ __launch_bounds__(256) void k_gemm1(const unsigned short* __restrict__ A,
                                               const unsigned short* __restrict__ Bt,
                                               float* __restrict__ hp) {
  __shared__ unsigned short As[128 * 32];
  __shared__ unsigned short Bs[128 * 32];
  const int tid  = threadIdx.x;
  const int w    = tid >> 6;
  const int lane = tid & 63;
  const int gx = blockIdx.x & 7;     // N tile (1024/128)
  const int gy = blockIdx.x >> 3;    // M tile (2048/128)
  const int kb = blockIdx.y;         // split-K chunk
  const int wr = w >> 1, wc = w & 1;

  f32x4 acc[4][4];
  const f32x4 zero = {0.f, 0.f, 0.f, 0.f};
#pragma unroll
  for (int m = 0; m < 4; ++m)
#pragma unroll
    for (int n = 0; n < 4; ++n) acc[m][n] = zero;

  // staging: 8 wave-chunks of 1024B each cover the 128x32 bf16 tile (8KB)
  const int off0 = (2 * w) * 1024 + lane * 16;  // byte offset in tile
  const int off1 = off0 + 1024;
  const int row0 = off0 >> 6, cu0 = (off0 & 63) >> 1;
  const int row1 = off1 >> 6, cu1 = (off1 & 63) >> 1;
  const int kstart = kb * (196 * 32);

  const unsigned short* gA0 = A  + (size_t)(gy * 128 + row0) * KTOT + kstart + cu0;
  const unsigned short* gA1 = A  + (size_t)(gy * 128 + row1) * KTOT + kstart + cu1;
  const unsigned short* gB0 = Bt + (size_t)(gx * 128 + row0) * KTOT + kstart + cu0;
  const unsigned short* gB1 = Bt + (size_t)(gx * 128 + row1) * KTOT + kstart + cu1;
  unsigned short* lA0 = &As[(2 * w) * 512];
  unsigned short* lA1 = &As[(2 * w) * 512 + 512];
  unsigned short* lB0 = &Bs[(2 * w) * 512];
  unsigned short* lB1 = &Bs[(2 * w) * 512 + 512];

  const int ar = (wr * 64 + (lane & 15)) * 32 + (lane >> 4) * 8;
  const int br = (wc * 64 + (lane & 15)) * 32 + (lane >> 4) * 8;

  for (int kk = 0; kk < 196; ++kk) {
    gload16(gA0, lA0); gload16(gA1, lA1);
    gload16(gB0, lB0); gload16(gB1, lB1);
    gA0 += 32; gA1 += 32; gB0 += 32; gB1 += 32;
    __syncthreads();                      // drains vmcnt -> LDS tile ready
    bf16x8 af[4], bf[4];
#pragma unroll
    for (int m = 0; m < 4; ++m)
      af[m] = *reinterpret_cast<const bf16x8*>(&As[ar + m * 16 * 32]);
#pragma unroll
    for (int n = 0; n < 4; ++n)
      bf[n] = *reinterpret_cast<const bf16x8*>(&Bs[br + n * 16 * 32]);
#pragma unroll
    for (int m = 0; m < 4; ++m)
#pragma unroll
      for (int n = 0; n < 4; ++n)
        acc[m][n] = __builtin_amdgcn_mfma_f32_16x16x32_bf16(af[m], bf[n], acc[m][n], 0, 0, 0);
    __syncthreads();                      // protect LDS before next stage
  }

  float* out = hp + (size_t)kb * (NBOX * HID);
  const int r0 = gy * 128 + wr * 64 + ((lane >> 4) << 2);
  const int c0 = gx * 128 + wc * 64 + (lane & 15);
#pragma unroll
  for (int m = 0; m < 4; ++m)
#pragma unroll
    for (int n = 0; n < 4; ++n) {
      int col = c0 + n * 16;
#pragma unroll
      for (int j = 0; j < 4; ++j) {
        int row = r0 + m * 16 + j;       // C/D: col=lane&15, row=(lane>>4)*4+j
        out[(size_t)row * HID + col] = acc[m][n][j];
      }
    }
}

// ---- kernel 6: sum split-K partials + bias + ReLU
__global__ __launch_bounds__(256) void k_combine(const float* __restrict__ hp,
                                                 const float* __restrict__ b1,
                                                 float* __restrict__ hidden) {
  int id = blockIdx.x * 256 + threadIdx.x;   // 2048*1024
  float v = hp[id] + hp[id + 2097152] + hp[id + 2 * 2097152] + hp[id + 3 * 2097152]
          + b1[id & 1023];
  hidden[id] = fmaxf(v, 0.f);
}

// ---- kernel 7: GEMM2 + BCE, one block per box row
__global__ __launch_bounds__(128) void k_gemm2(const float* __restrict__ hidden,
                                               const float* __restrict__ W2,
                                               const float* __restrict__ b2,
                                               const float* __restrict__ gtc,
                                               const int* __restrict__ assign,
                                               float* __restrict__ per) {
  __shared__ float hs[1024];
  __shared__ float lb[80];
  int n = blockIdx.x;
  int tid = threadIdx.x;
  for (int i = tid; i < 1024; i += 128) hs[i] = hidden[(size_t)n * 1024 + i];
  __syncthreads();
  if (tid < 80) {
    const float* wp = W2 + tid;
    float a0 = 0.f, a1 = 0.f, a2 = 0.f, a3 = 0.f;
    for (int k = 0; k < 1024; k += 4) {
      a0 += hs[k]     * wp[(size_t)k * 80];
      a1 += hs[k + 1] * wp[(size_t)(k + 1) * 80];
      a2 += hs[k + 2] * wp[(size_t)(k + 2) * 80];
      a3 += hs[k + 3] * wp[(size_t)(k + 3) * 80];
    }
    float x = (a0 + a1) + (a2 + a3) + b2[tid];
    int b = n >> 9;
    float y = gtc[((b << 5) + assign[n]) * 80 + tid];
    float c = log1pf(expf(-fabsf(x)));
    float spp = fmaxf(x, 0.f) + c;    // softplus(x)
    float spn = fmaxf(-x, 0.f) + c;   // softplus(-x)
    lb[tid] = y * spn + (1.f - y) * spp;
  }
  __syncthreads();
  if (tid == 0) {
    float s = 0.f;
    for (int i = 0; i < 80; ++i) s += lb[i];
    per[n] = s * (1.f / 80.f);
  }
}

// ---- kernel 8: fg-masked per-batch mean -> losses[4]
__global__ __launch_bounds__(512) void k_reduce(const float* __restrict__ per,
                                                const float* __restrict__ max_iou,
                                                const int* __restrict__ flag,
                                                float* __restrict__ out) {
  __shared__ float sv[8], sf[8];
  int b = blockIdx.x, tid = threadIdx.x;
  float thr = (*flag) ? 0.85f : 0.5f;
  int n = b * 512 + tid;
  float f = (max_iou[n] >= thr) ? 1.f : 0.f;
  float v = per[n] * f;
#pragma unroll
  for (int o = 32; o > 0; o >>= 1) {
    v += __shfl_down(v, o);
    f += __shfl_down(f, o);
  }
  int wv = tid >> 6;
  if ((tid & 63) == 0) { sv[wv] = v; sf[wv] = f; }
  __syncthreads();
  if (tid == 0) {
    float S = 0.f, F = 0.f;
#pragma unroll
    for (int i = 0; i < 8; ++i) { S += sv[i]; F += sf[i]; }
    out[b] = (F > 0.f) ? S / fmaxf(F, 1.f) : 0.f;
  }
}

extern "C" void kernel_launch(void* const* d_in, const int* in_sizes, int n_in,
                              void* d_out, int out_size, void* d_ws, size_t ws_size,
                              hipStream_t stream) {
  const float* feature = (const float*)d_in[0];
  const float* prop    = (const float*)d_in[1];
  const float* gtb     = (const float*)d_in[2];
  const float* gtc     = (const float*)d_in[3];
  const float* W1      = (const float*)d_in[4];
  const float* b1      = (const float*)d_in[5];
  const float* W2      = (const float*)d_in[6];
  const float* b2      = (const float*)d_in[7];
  const void*  ihp     = d_in[8];
  const void*  iwp     = d_in[9];

  char* ws = (char*)d_ws;
  size_t off = 0;
  float* fbhwc = (float*)(ws + off);            off += 1605632;     // 401408 f32
  unsigned short* W1T   = (unsigned short*)(ws + off); off += 51380224;  // 1024x25088 bf16
  unsigned short* Apool = (unsigned short*)(ws + off); off += 102760448; // 2048x25088 bf16
  float* hp     = (float*)(ws + off);           off += 4 * 8388608; // 4 split-K partials
  float* hidden = (float*)(ws + off);           off += 8388608;
  float* max_iou = (float*)(ws + off);          off += 8192;
  int*   assign  = (int*)(ws + off);            off += 8192;
  float* per     = (float*)(ws + off);          off += 8192;
  int*   flag    = (int*)(ws + off);            off += 256;

  hipMemsetAsync(flag, 0, sizeof(int), stream);
  k_meant  <<<1568, 256, 0, stream>>>(feature, fbhwc);
  k_iou    <<<8, 256, 0, stream>>>(prop, gtb, max_iou, assign, flag);
  k_w1t    <<<dim3(784, 32), 256, 0, stream>>>(W1, W1T);
  k_roipool<<<2048, 256, 0, stream>>>(fbhwc, prop, ihp, iwp, Apool);
  k_gemm1  <<<dim3(128, 4), 256, 0, stream>>>(Apool, W1T, hp);
  k_combine<<<8192, 256, 0, stream>>>(hp, b1, hidden);
  k_gemm2  <<<2048, 128, 0, stream>>>(hidden, W2, b2, gtc, assign, per);
  k_reduce <<<4, 512, 0, stream>>>(per, max_iou, flag, (float*)d_out);
}

// Round 2
// 234.346 us; speedup vs baseline: 1.3714x; 1.3714x over previous
//
#include <hip/hip_runtime.h>
#include <cstdint>
#include <cstddef>

#define KTOT 25088   // C*P*P = 512*49 (K-permuted: k' = bin*512 + c)
#define NBOX 2048
#define HID  1024

typedef __bf16 bf16x8 __attribute__((ext_vector_type(8)));
typedef float  f32x4  __attribute__((ext_vector_type(4)));

__device__ __forceinline__ unsigned short f2bf(float f) {
  union { float f; unsigned u; } v; v.f = f;
  unsigned r = v.u + 0x7FFFu + ((v.u >> 16) & 1u);   // RNE
  return (unsigned short)(r >> 16);
}

__device__ __forceinline__ float scalar_f(const void* p) {
  int iv = *(const int*)p;
  if (iv > 0 && iv < (1 << 20)) return (float)iv;
  return *(const float*)p;
}

// ---- kernel 1: mean over T + transpose -> fbhwc (B,14,14,C) f32
__global__ __launch_bounds__(256) void k_meant(const float* __restrict__ feature,
                                               float* __restrict__ fbhwc) {
  int id = blockIdx.x * 256 + threadIdx.x;
  if (id >= 4 * 512 * 196) return;
  int pix = id % 196;
  int c   = (id / 196) & 511;
  int b   = id / (196 * 512);
  const float* p = feature + ((size_t)(b * 512 + c) * 8) * 196 + pix;
  float s = 0.f;
#pragma unroll
  for (int t = 0; t < 8; ++t) s += p[t * 196];
  fbhwc[((size_t)(b * 196 + pix)) * 512 + c] = s * 0.125f;
}

// ---- kernel 2: IoU max/argmax + any_fg flag
__global__ __launch_bounds__(256) void k_iou(const float* __restrict__ prop,
                                             const float* __restrict__ gtb,
                                             float* __restrict__ max_iou,
                                             int* __restrict__ assign,
                                             int* __restrict__ flag) {
  __shared__ float g[128];
  int gid = blockIdx.x * 256 + threadIdx.x;
  int b = gid >> 9;
  if (threadIdx.x < 128) g[threadIdx.x] = gtb[b * 128 + threadIdx.x];
  __syncthreads();
  float x1 = prop[gid * 4 + 0], y1 = prop[gid * 4 + 1];
  float x2 = prop[gid * 4 + 2], y2 = prop[gid * 4 + 3];
  float aa = (x2 - x1) * (y2 - y1);
  float best = -1e30f; int arg = 0;
  for (int m = 0; m < 32; ++m) {
    float gx1 = g[m*4], gy1 = g[m*4+1], gx2 = g[m*4+2], gy2 = g[m*4+3];
    float iw = fmaxf(fminf(x2, gx2) - fmaxf(x1, gx1), 0.f);
    float ih = fmaxf(fminf(y2, gy2) - fmaxf(y1, gy1), 0.f);
    float inter = iw * ih;
    float ab = (gx2 - gx1) * (gy2 - gy1);
    float iou = inter / (aa + ab - inter + 1e-8f);
    if (iou > best) { best = iou; arg = m; }
  }
  max_iou[gid] = best; assign[gid] = arg;
  if (best >= 0.85f) atomicOr(flag, 1);
}

// ---- kernel 3: W1 -> W1T (1024 x 25088 bf16), col k'=bin*512+c
__global__ __launch_bounds__(256) void k_w1t(const float* __restrict__ W1,
                                             unsigned short* __restrict__ W1T) {
  __shared__ unsigned short tile[32][33];
  int kp0 = blockIdx.x * 32;
  int h0  = blockIdx.y * 32;
  int tj = threadIdx.x & 31;
  int ti = threadIdx.x >> 5;
#pragma unroll
  for (int r = 0; r < 4; ++r) {
    int i = ti + r * 8;
    int kp = kp0 + i;
    int srow = (kp & 511) * 49 + (kp >> 9);
    tile[i][tj] = f2bf(W1[(size_t)srow * 1024 + h0 + tj]);
  }
  __syncthreads();
#pragma unroll
  for (int r = 0; r < 4; ++r) {
    int hi = ti + r * 8;
    W1T[(size_t)(h0 + hi) * KTOT + kp0 + tj] = tile[tj][hi];
  }
}

// ---- kernel 4: ROI-pool, vectorized: float4 gathers, uint2 (4xbf16) stores
__global__ __launch_bounds__(256) void k_roipool(const float* __restrict__ fbhwc,
                                                 const float* __restrict__ prop,
                                                 const void* ihp, const void* iwp,
                                                 unsigned short* __restrict__ Apool) {
  int n = blockIdx.x;
  int tid = threadIdx.x;
  float sy = 14.f / scalar_f(ihp);
  float sx = 14.f / scalar_f(iwp);
  float bx1 = prop[n*4+0]*sx, by1 = prop[n*4+1]*sy;
  float bx2 = prop[n*4+2]*sx, by2 = prop[n*4+3]*sy;
  const float* fb = fbhwc + (size_t)(n >> 9) * 196 * 512;
  unsigned short* arow = Apool + (size_t)n * KTOT;
  int c4 = (tid & 127) << 2;
  int bh = tid >> 7;                        // wave-uniform (waves 0-1 vs 2-3)
  for (int b2i = 0; b2i < 49; b2i += 2) {
    int bin = b2i + bh;
    if (bin >= 49) continue;
    int py = bin / 7, px = bin - py * 7;
    float y = by1 + ((py + 0.5f) * (1.f/7.f)) * (by2 - by1) - 0.5f;
    float x = bx1 + ((px + 0.5f) * (1.f/7.f)) * (bx2 - bx1) - 0.5f;
    float y0f = floorf(y), x0f = floorf(x);
    float wy = y - y0f, wx = x - x0f;
    int y0  = min(max((int)y0f, 0), 13);
    int y1i = min(max((int)y0f + 1, 0), 13);
    int x0  = min(max((int)x0f, 0), 13);
    int x1i = min(max((int)x0f + 1, 0), 13);
    float w00 = (1.f - wy) * (1.f - wx), w01 = (1.f - wy) * wx;
    float w10 = wy * (1.f - wx),         w11 = wy * wx;
    const float4 f00 = *(const float4*)(fb + (y0 * 14 + x0 ) * 512 + c4);
    const float4 f01 = *(const float4*)(fb + (y0 * 14 + x1i) * 512 + c4);
    const float4 f10 = *(const float4*)(fb + (y1i * 14 + x0 ) * 512 + c4);
    const float4 f11 = *(const float4*)(fb + (y1i * 14 + x1i) * 512 + c4);
    float vx = f00.x*w00 + f01.x*w01 + f10.x*w10 + f11.x*w11;
    float vy = f00.y*w00 + f01.y*w01 + f10.y*w10 + f11.y*w11;
    float vz = f00.z*w00 + f01.z*w01 + f10.z*w10 + f11.z*w11;
    float vw = f00.w*w00 + f01.w*w01 + f10.w*w10 + f11.w*w11;
    unsigned lo = (unsigned)f2bf(vx) | ((unsigned)f2bf(vy) << 16);
    unsigned hi = (unsigned)f2bf(vz) | ((unsigned)f2bf(vw) << 16);
    *(uint2*)(arow + bin * 512 + c4) = make_uint2(lo, hi);
  }
}

// ---- GEMM (bf16, 128x128 tile, BK=32, 2-phase prefetch, LDS quad-swizzle, XCD swizzle)
__device__ __forceinline__ void gload16(const unsigned short* g, unsigned short* l) {
  __builtin_amdgcn_global_load_lds(
      (const __attribute__((address_space(1))) unsigned int*)g,
      (__attribute__((address_space(3))) unsigned int*)l, 16, 0, 0);
}

template<int OUTBF>
__global__ __launch_bounds__(256, 4) void k_gemm(
    const unsigned short* __restrict__ A,   // (mTiles*128) x Kst bf16 row-major
    const unsigned short* __restrict__ B,   // (nTiles*128) x Kst bf16 row-major
    void* __restrict__ outp,                // split-K partials
    int Kst, int kIters, int nTileBits, int mTileBits, int ldc)
{
  __shared__ unsigned short As[2][4096];
  __shared__ unsigned short Bs[2][4096];
  const int tid  = threadIdx.x;
  const int w    = tid >> 6;
  const int lane = tid & 63;
  // bijective XCD swizzle (nwg % 8 == 0)
  const int nwg = (int)gridDim.x, cpx = nwg >> 3;
  const int bid = (int)blockIdx.x;
  const int wg  = (bid & 7) * cpx + (bid >> 3);
  const int kb  = wg >> (mTileBits + nTileBits);
  const int rem = wg & ((1 << (mTileBits + nTileBits)) - 1);
  const int gy  = rem >> nTileBits;
  const int gx  = rem & ((1 << nTileBits) - 1);
  const int wr = w >> 1, wc = w & 1;

  f32x4 acc[4][4];
  const f32x4 zero = {0.f, 0.f, 0.f, 0.f};
#pragma unroll
  for (int m = 0; m < 4; ++m)
#pragma unroll
    for (int n = 0; n < 4; ++n) acc[m][n] = zero;

  // staging geometry: wave w covers rows 32w..32w+31 in two 16-row chunks.
  // LDS tile row = 64B (32 bf16) = 4 quads of 16B. Stored quad = q ^ ((row>>1)&3)
  // so the 16-lane ds_read_b128 column read spreads over all 8 bank groups.
  const int r0   = 32 * w + (lane >> 2);
  const int qsrc = (lane & 3) ^ ((lane >> 3) & 3);  // = (q ^ s(row)) for this lane
  const size_t kbase = (size_t)kb * kIters * 32;
  const unsigned short* gA = A + (size_t)(gy * 128 + r0) * Kst + kbase + qsrc * 8;
  const unsigned short* gB = B + (size_t)(gx * 128 + r0) * Kst + kbase + qsrc * 8;
  const int ldst = r0 * 32 + (lane & 3) * 8;        // linear LDS dest (ushort units)

  // fragment read offsets (with matching swizzle on the quad index)
  const int swq = ((lane >> 4) ^ ((lane >> 1) & 3)) * 8;
  const int ar = (wr * 64 + (lane & 15)) * 32 + swq;
  const int br = (wc * 64 + (lane & 15)) * 32 + swq;

#define STAGE(bufi, it) do {                                         \
    const unsigned short* pa = gA + (size_t)(it) * 32;               \
    const unsigned short* pb = gB + (size_t)(it) * 32;               \
    gload16(pa,                      &As[bufi][ldst]);               \
    gload16(pa + (size_t)16 * Kst,   &As[bufi][ldst + 512]);         \
    gload16(pb,                      &Bs[bufi][ldst]);               \
    gload16(pb + (size_t)16 * Kst,   &Bs[bufi][ldst + 512]);         \
  } while (0)

  STAGE(0, 0);
  int cur = 0;
  for (int kk = 0; kk < kIters; ++kk) {
    __syncthreads();                       // drains vmcnt: buf[cur] ready; prev reads of buf[cur^1] done
    if (kk + 1 < kIters) STAGE(cur ^ 1, kk + 1);   // prefetch overlaps this iter's compute
    bf16x8 af[4], bfr[4];
#pragma unroll
    for (int m = 0; m < 4; ++m)
      af[m] = *reinterpret_cast<const bf16x8*>(&As[cur][ar + m * 512]);
#pragma unroll
    for (int n = 0; n < 4; ++n)
      bfr[n] = *reinterpret_cast<const bf16x8*>(&Bs[cur][br + n * 512]);
#pragma unroll
    for (int m = 0; m < 4; ++m)
#pragma unroll
      for (int n = 0; n < 4; ++n)
        acc[m][n] = __builtin_amdgcn_mfma_f32_16x16x32_bf16(af[m], bfr[n], acc[m][n], 0, 0, 0);
    cur ^= 1;
  }
#undef STAGE

  const size_t M = (size_t)(1 << mTileBits) * 128;
  const size_t splitStride = M * (size_t)ldc;
  const int r0o = gy * 128 + wr * 64 + ((lane >> 4) << 2);
  const int c0o = gx * 128 + wc * 64 + (lane & 15);
  if (OUTBF) {
    unsigned short* o = (unsigned short*)outp + (size_t)kb * splitStride;
#pragma unroll
    for (int m = 0; m < 4; ++m)
#pragma unroll
      for (int n = 0; n < 4; ++n)
#pragma unroll
        for (int j = 0; j < 4; ++j)
          o[(size_t)(r0o + m * 16 + j) * ldc + c0o + n * 16] = f2bf(acc[m][n][j]);
  } else {
    float* o = (float*)outp + (size_t)kb * splitStride;
#pragma unroll
    for (int m = 0; m < 4; ++m)
#pragma unroll
      for (int n = 0; n < 4; ++n)
#pragma unroll
        for (int j = 0; j < 4; ++j)
          o[(size_t)(r0o + m * 16 + j) * ldc + c0o + n * 16] = acc[m][n][j];
  }
}

// ---- combine 8 bf16 split-K partials + bias + ReLU -> hidden bf16
__global__ __launch_bounds__(256) void k_combine(const unsigned short* __restrict__ hp,
                                                 const float* __restrict__ b1,
                                                 unsigned short* __restrict__ hidden) {
  int gid = blockIdx.x * 256 + threadIdx.x;    // 262144 total, 8 elems each
  int id8 = gid * 8;
  int h = id8 & 1023;
  float a[8];
#pragma unroll
  for (int j = 0; j < 8; ++j) a[j] = b1[h + j];
#pragma unroll
  for (int s = 0; s < 8; ++s) {
    uint4 u = *(const uint4*)(hp + (size_t)s * 2097152 + id8);
    unsigned uu[4] = {u.x, u.y, u.z, u.w};
#pragma unroll
    for (int q = 0; q < 4; ++q) {
      union { unsigned u; float f; } lo, hi;
      lo.u = uu[q] << 16; hi.u = uu[q] & 0xFFFF0000u;
      a[2*q]   += lo.f;
      a[2*q+1] += hi.f;
    }
  }
  unsigned out[4];
#pragma unroll
  for (int q = 0; q < 4; ++q) {
    unsigned l  = f2bf(fmaxf(a[2*q],   0.f));
    unsigned hh = f2bf(fmaxf(a[2*q+1], 0.f));
    out[q] = l | (hh << 16);
  }
  *(uint4*)(hidden + id8) = make_uint4(out[0], out[1], out[2], out[3]);
}

// ---- W2 (1024x80 f32) -> W2T (128x1024 bf16, zero-padded classes 80..127)
__global__ __launch_bounds__(256) void k_w2t(const float* __restrict__ W2,
                                             unsigned short* __restrict__ W2T) {
  int id = blockIdx.x * 256 + threadIdx.x;   // 131072
  int cls = id >> 10, k = id & 1023;
  float v = (cls < 80) ? W2[(size_t)k * 80 + cls] : 0.f;
  W2T[id] = f2bf(v);
}

// ---- BCE from gemm2 split-K partials (4 x 2048 x 128 f32)
__global__ __launch_bounds__(256) void k_bce(const float* __restrict__ hp2,
                                             const float* __restrict__ b2,
                                             const float* __restrict__ gtc,
                                             const int* __restrict__ assign,
                                             float* __restrict__ per) {
  __shared__ float red[256];
  int t = threadIdx.x;
  int box = t >> 4, li = t & 15;
  int n = blockIdx.x * 16 + box;
  int lab = ((n >> 9) * 32 + assign[n]) * 80;
  float s = 0.f;
#pragma unroll
  for (int j = 0; j < 5; ++j) {
    int c = li + 16 * j;
    size_t o = (size_t)n * 128 + c;
    float x = hp2[o] + hp2[o + 262144] + hp2[o + 524288] + hp2[o + 786432] + b2[c];
    float y = gtc[lab + c];
    float ce = log1pf(expf(-fabsf(x)));
    s += y * (fmaxf(-x, 0.f) + ce) + (1.f - y) * (fmaxf(x, 0.f) + ce);
  }
  red[t] = s;
  __syncthreads();
  if (li == 0) {
    float tot = 0.f;
#pragma unroll
    for (int i = 0; i < 16; ++i) tot += red[box * 16 + i];
    per[n] = tot * (1.f / 80.f);
  }
}

// ---- fg-masked per-batch mean -> losses[4]
__global__ __launch_bounds__(512) void k_reduce(const float* __restrict__ per,
                                                const float* __restrict__ max_iou,
                                                const int* __restrict__ flag,
                                                float* __restrict__ out) {
  __shared__ float sv[8], sf[8];
  int b = blockIdx.x, tid = threadIdx.x;
  float thr = (*flag) ? 0.85f : 0.5f;
  int n = b * 512 + tid;
  float f = (max_iou[n] >= thr) ? 1.f : 0.f;
  float v = per[n] * f;
#pragma unroll
  for (int o = 32; o > 0; o >>= 1) {
    v += __shfl_down(v, o);
    f += __shfl_down(f, o);
  }
  int wv = tid >> 6;
  if ((tid & 63) == 0) { sv[wv] = v; sf[wv] = f; }
  __syncthreads();
  if (tid == 0) {
    float S = 0.f, F = 0.f;
#pragma unroll
    for (int i = 0; i < 8; ++i) { S += sv[i]; F += sf[i]; }
    out[b] = (F > 0.f) ? S / fmaxf(F, 1.f) : 0.f;
  }
}

extern "C" void kernel_launch(void* const* d_in, const int* in_sizes, int n_in,
                              void* d_out, int out_size, void* d_ws, size_t ws_size,
                              hipStream_t stream) {
  const float* feature = (const float*)d_in[0];
  const float* prop    = (const float*)d_in[1];
  const float* gtb     = (const float*)d_in[2];
  const float* gtc     = (const float*)d_in[3];
  const float* W1      = (const float*)d_in[4];
  const float* b1      = (const float*)d_in[5];
  const float* W2      = (const float*)d_in[6];
  const float* b2      = (const float*)d_in[7];
  const void*  ihp     = d_in[8];
  const void*  iwp     = d_in[9];

  char* ws = (char*)d_ws;
  float*          fbhwc  = (float*)(ws);                          // 1,605,632 B
  unsigned short* W1T    = (unsigned short*)(ws + 1605632);       // 51,380,224 B
  unsigned short* Apool  = (unsigned short*)(ws + 52985856);      // 102,760,448 B
  unsigned short* hp     = (unsigned short*)(ws + 155746304);     // 33,554,432 B (8 splits bf16)
  float*          max_iou= (float*)(ws + 189300736);
  int*            assign = (int*)(ws + 189308928);
  float*          per    = (float*)(ws + 189317120);
  int*            flag   = (int*)(ws + 189325312);
  // regions reused after k_gemm1 consumed their producers:
  unsigned short* hidden = W1T;                                    // 4,194,304 B
  unsigned short* W2T    = Apool;                                  // 262,144 B
  float*          hp2    = (float*)((char*)Apool + 262144);        // 4,194,304 B

  hipMemsetAsync(flag, 0, sizeof(int), stream);
  k_meant  <<<1568, 256, 0, stream>>>(feature, fbhwc);
  k_iou    <<<8, 256, 0, stream>>>(prop, gtb, max_iou, assign, flag);
  k_w1t    <<<dim3(784, 32), 256, 0, stream>>>(W1, W1T);
  k_roipool<<<2048, 256, 0, stream>>>(fbhwc, prop, ihp, iwp, Apool);
  // GEMM1: M=2048 (16 tiles), N=1024 (8 tiles), K=25088, split-K=8 (98 iters)
  k_gemm<1><<<1024, 256, 0, stream>>>(Apool, W1T, hp, KTOT, 98, 3, 4, 1024);
  k_combine<<<1024, 256, 0, stream>>>(hp, b1, hidden);
  k_w2t    <<<512, 256, 0, stream>>>(W2, W2T);
  // GEMM2: M=2048 (16 tiles), N=128 (1 tile), K=1024, split-K=4 (8 iters)
  k_gemm<0><<<64, 256, 0, stream>>>(hidden, W2T, hp2, 1024, 8, 0, 4, 128);
  k_bce    <<<128, 256, 0, stream>>>(hp2, b2, gtc, assign, per);
  k_reduce <<<4, 512, 0, stream>>>(per, max_iou, flag, (float*)d_out);
}

// Round 3
// 231.592 us; speedup vs baseline: 1.3877x; 1.0119x over previous
//
#include <hip/hip_runtime.h>
#include <cstdint>
#include <cstddef>

#define KTOT 25088   // C*P*P = 512*49 (K-permuted: k' = bin*512 + c)
#define NBOX 2048
#define HID  1024

typedef __bf16 bf16x8 __attribute__((ext_vector_type(8)));
typedef float  f32x4  __attribute__((ext_vector_type(4)));

__device__ __forceinline__ unsigned short f2bf(float f) {
  union { float f; unsigned u; } v; v.f = f;
  unsigned r = v.u + 0x7FFFu + ((v.u >> 16) & 1u);   // RNE
  return (unsigned short)(r >> 16);
}

__device__ __forceinline__ float scalar_f(const void* p) {
  int iv = *(const int*)p;
  if (iv > 0 && iv < (1 << 20)) return (float)iv;
  return *(const float*)p;
}

// ---- kernel 1: mean over T + transpose -> fbhwc (B,14,14,C) f32
__global__ __launch_bounds__(256) void k_meant(const float* __restrict__ feature,
                                               float* __restrict__ fbhwc) {
  int id = blockIdx.x * 256 + threadIdx.x;
  if (id >= 4 * 512 * 196) return;
  int pix = id % 196;
  int c   = (id / 196) & 511;
  int b   = id / (196 * 512);
  const float* p = feature + ((size_t)(b * 512 + c) * 8) * 196 + pix;
  float s = 0.f;
#pragma unroll
  for (int t = 0; t < 8; ++t) s += p[t * 196];
  fbhwc[((size_t)(b * 196 + pix)) * 512 + c] = s * 0.125f;
}

// ---- kernel 2: IoU max/argmax + any_fg flag
__global__ __launch_bounds__(256) void k_iou(const float* __restrict__ prop,
                                             const float* __restrict__ gtb,
                                             float* __restrict__ max_iou,
                                             int* __restrict__ assign,
                                             int* __restrict__ flag) {
  __shared__ float g[128];
  int gid = blockIdx.x * 256 + threadIdx.x;
  int b = gid >> 9;
  if (threadIdx.x < 128) g[threadIdx.x] = gtb[b * 128 + threadIdx.x];
  __syncthreads();
  float x1 = prop[gid * 4 + 0], y1 = prop[gid * 4 + 1];
  float x2 = prop[gid * 4 + 2], y2 = prop[gid * 4 + 3];
  float aa = (x2 - x1) * (y2 - y1);
  float best = -1e30f; int arg = 0;
  for (int m = 0; m < 32; ++m) {
    float gx1 = g[m*4], gy1 = g[m*4+1], gx2 = g[m*4+2], gy2 = g[m*4+3];
    float iw = fmaxf(fminf(x2, gx2) - fmaxf(x1, gx1), 0.f);
    float ih = fmaxf(fminf(y2, gy2) - fmaxf(y1, gy1), 0.f);
    float inter = iw * ih;
    float ab = (gx2 - gx1) * (gy2 - gy1);
    float iou = inter / (aa + ab - inter + 1e-8f);
    if (iou > best) { best = iou; arg = m; }
  }
  max_iou[gid] = best; assign[gid] = arg;
  if (best >= 0.85f) atomicOr(flag, 1);
}

// ---- kernel 3: W1 -> W1T (1024 x 25088 bf16), col k'=bin*512+c
__global__ __launch_bounds__(256) void k_w1t(const float* __restrict__ W1,
                                             unsigned short* __restrict__ W1T) {
  __shared__ unsigned short tile[32][33];
  int kp0 = blockIdx.x * 32;
  int h0  = blockIdx.y * 32;
  int tj = threadIdx.x & 31;
  int ti = threadIdx.x >> 5;
#pragma unroll
  for (int r = 0; r < 4; ++r) {
    int i = ti + r * 8;
    int kp = kp0 + i;
    int srow = (kp & 511) * 49 + (kp >> 9);
    tile[i][tj] = f2bf(W1[(size_t)srow * 1024 + h0 + tj]);
  }
  __syncthreads();
#pragma unroll
  for (int r = 0; r < 4; ++r) {
    int hi = ti + r * 8;
    W1T[(size_t)(h0 + hi) * KTOT + kp0 + tj] = tile[tj][hi];
  }
}

// ---- kernel 4: ROI-pool, vectorized: float4 gathers, uint2 (4xbf16) stores
__global__ __launch_bounds__(256) void k_roipool(const float* __restrict__ fbhwc,
                                                 const float* __restrict__ prop,
                                                 const void* ihp, const void* iwp,
                                                 unsigned short* __restrict__ Apool) {
  int n = blockIdx.x;
  int tid = threadIdx.x;
  float sy = 14.f / scalar_f(ihp);
  float sx = 14.f / scalar_f(iwp);
  float bx1 = prop[n*4+0]*sx, by1 = prop[n*4+1]*sy;
  float bx2 = prop[n*4+2]*sx, by2 = prop[n*4+3]*sy;
  const float* fb = fbhwc + (size_t)(n >> 9) * 196 * 512;
  unsigned short* arow = Apool + (size_t)n * KTOT;
  int c4 = (tid & 127) << 2;
  int bh = tid >> 7;                        // wave-uniform (waves 0-1 vs 2-3)
  for (int b2i = 0; b2i < 49; b2i += 2) {
    int bin = b2i + bh;
    if (bin >= 49) continue;
    int py = bin / 7, px = bin - py * 7;
    float y = by1 + ((py + 0.5f) * (1.f/7.f)) * (by2 - by1) - 0.5f;
    float x = bx1 + ((px + 0.5f) * (1.f/7.f)) * (bx2 - bx1) - 0.5f;
    float y0f = floorf(y), x0f = floorf(x);
    float wy = y - y0f, wx = x - x0f;
    int y0  = min(max((int)y0f, 0), 13);
    int y1i = min(max((int)y0f + 1, 0), 13);
    int x0  = min(max((int)x0f, 0), 13);
    int x1i = min(max((int)x0f + 1, 0), 13);
    float w00 = (1.f - wy) * (1.f - wx), w01 = (1.f - wy) * wx;
    float w10 = wy * (1.f - wx),         w11 = wy * wx;
    const float4 f00 = *(const float4*)(fb + (y0 * 14 + x0 ) * 512 + c4);
    const float4 f01 = *(const float4*)(fb + (y0 * 14 + x1i) * 512 + c4);
    const float4 f10 = *(const float4*)(fb + (y1i * 14 + x0 ) * 512 + c4);
    const float4 f11 = *(const float4*)(fb + (y1i * 14 + x1i) * 512 + c4);
    float vx = f00.x*w00 + f01.x*w01 + f10.x*w10 + f11.x*w11;
    float vy = f00.y*w00 + f01.y*w01 + f10.y*w10 + f11.y*w11;
    float vz = f00.z*w00 + f01.z*w01 + f10.z*w10 + f11.z*w11;
    float vw = f00.w*w00 + f01.w*w01 + f10.w*w10 + f11.w*w11;
    unsigned lo = (unsigned)f2bf(vx) | ((unsigned)f2bf(vy) << 16);
    unsigned hi = (unsigned)f2bf(vz) | ((unsigned)f2bf(vw) << 16);
    *(uint2*)(arow + bin * 512 + c4) = make_uint2(lo, hi);
  }
}

// ---- GEMM (bf16, 128x128 tile, BK=32, 2-phase prefetch, LDS quad-swizzle, XCD swizzle)
__device__ __forceinline__ void gload16(const unsigned short* g, unsigned short* l) {
  __builtin_amdgcn_global_load_lds(
      (const __attribute__((address_space(1))) unsigned int*)g,
      (__attribute__((address_space(3))) unsigned int*)l, 16, 0, 0);
}

template<int OUTBF>
__global__ __launch_bounds__(256, 4) void k_gemm(
    const unsigned short* __restrict__ A,   // (mTiles*128) x Kst bf16 row-major
    const unsigned short* __restrict__ B,   // (nTiles*128) x Kst bf16 row-major
    void* __restrict__ outp,                // split-K partials
    int Kst, int kIters, int nTileBits, int mTileBits, int ldc)
{
  __shared__ unsigned short As[2][4096];
  __shared__ unsigned short Bs[2][4096];
  const int tid  = threadIdx.x;
  const int w    = tid >> 6;
  const int lane = tid & 63;
  // bijective XCD swizzle (nwg % 8 == 0)
  const int nwg = (int)gridDim.x, cpx = nwg >> 3;
  const int bid = (int)blockIdx.x;
  const int wg  = (bid & 7) * cpx + (bid >> 3);
  const int kb  = wg >> (mTileBits + nTileBits);
  const int rem = wg & ((1 << (mTileBits + nTileBits)) - 1);
  const int gy  = rem >> nTileBits;
  const int gx  = rem & ((1 << nTileBits) - 1);
  const int wr = w >> 1, wc = w & 1;

  f32x4 acc[4][4];
  const f32x4 zero = {0.f, 0.f, 0.f, 0.f};
#pragma unroll
  for (int m = 0; m < 4; ++m)
#pragma unroll
    for (int n = 0; n < 4; ++n) acc[m][n] = zero;

  // staging geometry: wave w covers rows 32w..32w+31 in two 16-row chunks.
  // LDS tile row = 64B (32 bf16) = 4 quads of 16B. Stored quad = q ^ ((row>>1)&3)
  // so the 16-lane ds_read_b128 column read spreads over all 8 bank groups.
  const int r0   = 32 * w + (lane >> 2);
  const int qsrc = (lane & 3) ^ ((lane >> 3) & 3);  // = (q ^ s(row)) for this lane
  const size_t kbase = (size_t)kb * kIters * 32;
  const unsigned short* gA = A + (size_t)(gy * 128 + r0) * Kst + kbase + qsrc * 8;
  const unsigned short* gB = B + (size_t)(gx * 128 + r0) * Kst + kbase + qsrc * 8;
  const int ldst = r0 * 32 + (lane & 3) * 8;        // linear LDS dest (ushort units)

  // fragment read offsets (with matching swizzle on the quad index)
  const int swq = ((lane >> 4) ^ ((lane >> 1) & 3)) * 8;
  const int ar = (wr * 64 + (lane & 15)) * 32 + swq;
  const int br = (wc * 64 + (lane & 15)) * 32 + swq;

#define STAGE(bufi, it) do {                                         \
    const unsigned short* pa = gA + (size_t)(it) * 32;               \
    const unsigned short* pb = gB + (size_t)(it) * 32;               \
    gload16(pa,                      &As[bufi][ldst]);               \
    gload16(pa + (size_t)16 * Kst,   &As[bufi][ldst + 512]);         \
    gload16(pb,                      &Bs[bufi][ldst]);               \
    gload16(pb + (size_t)16 * Kst,   &Bs[bufi][ldst + 512]);         \
  } while (0)

  STAGE(0, 0);
  int cur = 0;
  for (int kk = 0; kk < kIters; ++kk) {
    __syncthreads();                       // drains vmcnt: buf[cur] ready; prev reads of buf[cur^1] done
    if (kk + 1 < kIters) STAGE(cur ^ 1, kk + 1);   // prefetch overlaps this iter's compute
    bf16x8 af[4], bfr[4];
#pragma unroll
    for (int m = 0; m < 4; ++m)
      af[m] = *reinterpret_cast<const bf16x8*>(&As[cur][ar + m * 512]);
#pragma unroll
    for (int n = 0; n < 4; ++n)
      bfr[n] = *reinterpret_cast<const bf16x8*>(&Bs[cur][br + n * 512]);
#pragma unroll
    for (int m = 0; m < 4; ++m)
#pragma unroll
      for (int n = 0; n < 4; ++n)
        acc[m][n] = __builtin_amdgcn_mfma_f32_16x16x32_bf16(af[m], bfr[n], acc[m][n], 0, 0, 0);
    cur ^= 1;
  }
#undef STAGE

  const size_t M = (size_t)(1 << mTileBits) * 128;
  const size_t splitStride = M * (size_t)ldc;
  const int r0o = gy * 128 + wr * 64 + ((lane >> 4) << 2);
  const int c0o = gx * 128 + wc * 64 + (lane & 15);
  if (OUTBF) {
    unsigned short* o = (unsigned short*)outp + (size_t)kb * splitStride;
#pragma unroll
    for (int m = 0; m < 4; ++m)
#pragma unroll
      for (int n = 0; n < 4; ++n)
#pragma unroll
        for (int j = 0; j < 4; ++j)
          o[(size_t)(r0o + m * 16 + j) * ldc + c0o + n * 16] = f2bf(acc[m][n][j]);
  } else {
    float* o = (float*)outp + (size_t)kb * splitStride;
#pragma unroll
    for (int m = 0; m < 4; ++m)
#pragma unroll
      for (int n = 0; n < 4; ++n)
#pragma unroll
        for (int j = 0; j < 4; ++j)
          o[(size_t)(r0o + m * 16 + j) * ldc + c0o + n * 16] = acc[m][n][j];
  }
}

// ---- combine 8 bf16 split-K partials + bias + ReLU -> hidden bf16
__global__ __launch_bounds__(256) void k_combine(const unsigned short* __restrict__ hp,
                                                 const float* __restrict__ b1,
                                                 unsigned short* __restrict__ hidden) {
  int gid = blockIdx.x * 256 + threadIdx.x;    // 262144 total, 8 elems each
  int id8 = gid * 8;
  int h = id8 & 1023;
  float a[8];
#pragma unroll
  for (int j = 0; j < 8; ++j) a[j] = b1[h + j];
#pragma unroll
  for (int s = 0; s < 8; ++s) {
    uint4 u = *(const uint4*)(hp + (size_t)s * 2097152 + id8);
    unsigned uu[4] = {u.x, u.y, u.z, u.w};
#pragma unroll
    for (int q = 0; q < 4; ++q) {
      union { unsigned u; float f; } lo, hi;
      lo.u = uu[q] << 16; hi.u = uu[q] & 0xFFFF0000u;
      a[2*q]   += lo.f;
      a[2*q+1] += hi.f;
    }
  }
  unsigned out[4];
#pragma unroll
  for (int q = 0; q < 4; ++q) {
    unsigned l  = f2bf(fmaxf(a[2*q],   0.f));
    unsigned hh = f2bf(fmaxf(a[2*q+1], 0.f));
    out[q] = l | (hh << 16);
  }
  *(uint4*)(hidden + id8) = make_uint4(out[0], out[1], out[2], out[3]);
}

// ---- W2 (1024x80 f32) -> W2T (128x1024 bf16, zero-padded classes 80..127)
__global__ __launch_bounds__(256) void k_w2t(const float* __restrict__ W2,
                                             unsigned short* __restrict__ W2T) {
  int id = blockIdx.x * 256 + threadIdx.x;   // 131072
  int cls = id >> 10, k = id & 1023;
  float v = (cls < 80) ? W2[(size_t)k * 80 + cls] : 0.f;
  W2T[id] = f2bf(v);
}

// ---- BCE from gemm2 split-K partials (4 x 2048 x 128 f32)
__global__ __launch_bounds__(256) void k_bce(const float* __restrict__ hp2,
                                             const float* __restrict__ b2,
                                             const float* __restrict__ gtc,
                                             const int* __restrict__ assign,
                                             float* __restrict__ per) {
  __shared__ float red[256];
  int t = threadIdx.x;
  int box = t >> 4, li = t & 15;
  int n = blockIdx.x * 16 + box;
  int lab = ((n >> 9) * 32 + assign[n]) * 80;
  float s = 0.f;
#pragma unroll
  for (int j = 0; j < 5; ++j) {
    int c = li + 16 * j;
    size_t o = (size_t)n * 128 + c;
    float x = hp2[o] + hp2[o + 262144] + hp2[o + 524288] + hp2[o + 786432] + b2[c];
    float y = gtc[lab + c];
    float ce = log1pf(expf(-fabsf(x)));
    s += y * (fmaxf(-x, 0.f) + ce) + (1.f - y) * (fmaxf(x, 0.f) + ce);
  }
  red[t] = s;
  __syncthreads();
  if (li == 0) {
    float tot = 0.f;
#pragma unroll
    for (int i = 0; i < 16; ++i) tot += red[box * 16 + i];
    per[n] = tot * (1.f / 80.f);
  }
}

// ---- fg-masked per-batch mean -> losses[4]
__global__ __launch_bounds__(512) void k_reduce(const float* __restrict__ per,
                                                const float* __restrict__ max_iou,
                                                const int* __restrict__ flag,
                                                float* __restrict__ out) {
  __shared__ float sv[8], sf[8];
  int b = blockIdx.x, tid = threadIdx.x;
  float thr = (*flag) ? 0.85f : 0.5f;
  int n = b * 512 + tid;
  float f = (max_iou[n] >= thr) ? 1.f : 0.f;
  float v = per[n] * f;
#pragma unroll
  for (int o = 32; o > 0; o >>= 1) {
    v += __shfl_down(v, o);
    f += __shfl_down(f, o);
  }
  int wv = tid >> 6;
  if ((tid & 63) == 0) { sv[wv] = v; sf[wv] = f; }
  __syncthreads();
  if (tid == 0) {
    float S = 0.f, F = 0.f;
#pragma unroll
    for (int i = 0; i < 8; ++i) { S += sv[i]; F += sf[i]; }
    out[b] = (F > 0.f) ? S / fmaxf(F, 1.f) : 0.f;
  }
}

extern "C" void kernel_launch(void* const* d_in, const int* in_sizes, int n_in,
                              void* d_out, int out_size, void* d_ws, size_t ws_size,
                              hipStream_t stream) {
  const float* feature = (const float*)d_in[0];
  const float* prop    = (const float*)d_in[1];
  const float* gtb     = (const float*)d_in[2];
  const float* gtc     = (const float*)d_in[3];
  const float* W1      = (const float*)d_in[4];
  const float* b1      = (const float*)d_in[5];
  const float* W2      = (const float*)d_in[6];
  const float* b2      = (const float*)d_in[7];
  const void*  ihp     = d_in[8];
  const void*  iwp     = d_in[9];

  char* ws = (char*)d_ws;
  float*          fbhwc  = (float*)(ws);                          // 1,605,632 B
  unsigned short* W1T    = (unsigned short*)(ws + 1605632);       // 51,380,224 B
  unsigned short* Apool  = (unsigned short*)(ws + 52985856);      // 102,760,448 B
  unsigned short* hp     = (unsigned short*)(ws + 155746304);     // 33,554,432 B (8 splits bf16)
  float*          max_iou= (float*)(ws + 189300736);
  int*            assign = (int*)(ws + 189308928);
  float*          per    = (float*)(ws + 189317120);
  int*            flag   = (int*)(ws + 189325312);
  // regions reused after k_gemm1 consumed their producers:
  unsigned short* hidden = W1T;                                    // 4,194,304 B
  unsigned short* W2T    = Apool;                                  // 262,144 B
  float*          hp2    = (float*)((char*)Apool + 262144);        // 4,194,304 B

  hipMemsetAsync(flag, 0, sizeof(int), stream);
  k_meant  <<<1568, 256, 0, stream>>>(feature, fbhwc);
  k_iou    <<<8, 256, 0, stream>>>(prop, gtb, max_iou, assign, flag);
  k_w1t    <<<dim3(784, 32), 256, 0, stream>>>(W1, W1T);
  k_roipool<<<2048, 256, 0, stream>>>(fbhwc, prop, ihp, iwp, Apool);
  // GEMM1: M=2048 (16 tiles), N=1024 (8 tiles), K=25088, split-K=8 (98 iters)
  k_gemm<1><<<1024, 256, 0, stream>>>(Apool, W1T, hp, KTOT, 98, 3, 4, 1024);
  k_combine<<<1024, 256, 0, stream>>>(hp, b1, hidden);
  k_w2t    <<<512, 256, 0, stream>>>(W2, W2T);
  // GEMM2: M=2048 (16 tiles), N=128 (1 tile), K=1024, split-K=4 (8 iters)
  k_gemm<0><<<64, 256, 0, stream>>>(hidden, W2T, hp2, 1024, 8, 0, 4, 128);
  k_bce    <<<128, 256, 0, stream>>>(hp2, b2, gtc, assign, per);
  k_reduce <<<4, 512, 0, stream>>>(per, max_iou, flag, (float*)d_out);
}

// Round 4
// 203.066 us; speedup vs baseline: 1.5827x; 1.1405x over previous
//
#include <hip/hip_runtime.h>
#include <cstdint>
#include <cstddef>

#define KTOT 25088   // C*P*P = 512*49 (K-permuted: k' = bin*512 + c)
#define NBOX 2048
#define HID  1024

typedef __bf16 bf16x8 __attribute__((ext_vector_type(8)));
typedef float  f32x4  __attribute__((ext_vector_type(4)));

__device__ __forceinline__ unsigned short f2bf(float f) {
  union { float f; unsigned u; } v; v.f = f;
  unsigned r = v.u + 0x7FFFu + ((v.u >> 16) & 1u);   // RNE
  return (unsigned short)(r >> 16);
}

__device__ __forceinline__ float scalar_f(const void* p) {
  int iv = *(const int*)p;
  if (iv > 0 && iv < (1 << 20)) return (float)iv;
  return *(const float*)p;
}

// ---- kernel 1: mean over T + transpose -> fbhwc (B,14,14,C) f32
__global__ __launch_bounds__(256) void k_meant(const float* __restrict__ feature,
                                               float* __restrict__ fbhwc) {
  int id = blockIdx.x * 256 + threadIdx.x;
  if (id >= 4 * 512 * 196) return;
  int pix = id % 196;
  int c   = (id / 196) & 511;
  int b   = id / (196 * 512);
  const float* p = feature + ((size_t)(b * 512 + c) * 8) * 196 + pix;
  float s = 0.f;
#pragma unroll
  for (int t = 0; t < 8; ++t) s += p[t * 196];
  fbhwc[((size_t)(b * 196 + pix)) * 512 + c] = s * 0.125f;
}

// ---- kernel 2: IoU max/argmax + any_fg flag
__global__ __launch_bounds__(256) void k_iou(const float* __restrict__ prop,
                                             const float* __restrict__ gtb,
                                             float* __restrict__ max_iou,
                                             int* __restrict__ assign,
                                             int* __restrict__ flag) {
  __shared__ float g[128];
  int gid = blockIdx.x * 256 + threadIdx.x;
  int b = gid >> 9;
  if (threadIdx.x < 128) g[threadIdx.x] = gtb[b * 128 + threadIdx.x];
  __syncthreads();
  float x1 = prop[gid * 4 + 0], y1 = prop[gid * 4 + 1];
  float x2 = prop[gid * 4 + 2], y2 = prop[gid * 4 + 3];
  float aa = (x2 - x1) * (y2 - y1);
  float best = -1e30f; int arg = 0;
  for (int m = 0; m < 32; ++m) {
    float gx1 = g[m*4], gy1 = g[m*4+1], gx2 = g[m*4+2], gy2 = g[m*4+3];
    float iw = fmaxf(fminf(x2, gx2) - fmaxf(x1, gx1), 0.f);
    float ih = fmaxf(fminf(y2, gy2) - fmaxf(y1, gy1), 0.f);
    float inter = iw * ih;
    float ab = (gx2 - gx1) * (gy2 - gy1);
    float iou = inter / (aa + ab - inter + 1e-8f);
    if (iou > best) { best = iou; arg = m; }
  }
  max_iou[gid] = best; assign[gid] = arg;
  if (best >= 0.85f) atomicOr(flag, 1);
}

// ---- kernel 3: W1 -> W1T (1024 x 25088 bf16), col k'=bin*512+c. 64x64 tiles.
__global__ __launch_bounds__(256) void k_w1t(const float* __restrict__ W1,
                                             unsigned short* __restrict__ W1T) {
  __shared__ unsigned short tile[64][68];
  int kp0 = blockIdx.x * 64;
  int h0  = blockIdx.y * 64;
  int t = threadIdx.x;
  int seg = t & 15, ro = t >> 4;
#pragma unroll
  for (int r = 0; r < 4; ++r) {
    int i = ro + r * 16;
    int kp = kp0 + i;
    int srow = (kp & 511) * 49 + (kp >> 9);
    float4 v = *(const float4*)(W1 + (size_t)srow * 1024 + h0 + seg * 4);
    tile[i][seg*4+0] = f2bf(v.x);
    tile[i][seg*4+1] = f2bf(v.y);
    tile[i][seg*4+2] = f2bf(v.z);
    tile[i][seg*4+3] = f2bf(v.w);
  }
  __syncthreads();
#pragma unroll
  for (int r = 0; r < 4; ++r) {
    int hi = ro + r * 16;
    unsigned a = tile[seg*4+0][hi];
    unsigned b = tile[seg*4+1][hi];
    unsigned c = tile[seg*4+2][hi];
    unsigned d = tile[seg*4+3][hi];
    *(uint2*)(W1T + (size_t)(h0+hi)*KTOT + kp0 + seg*4) =
        make_uint2(a | (b << 16), c | (d << 16));
  }
}

// ---- kernel 4: ROI-pool, vectorized
__global__ __launch_bounds__(256) void k_roipool(const float* __restrict__ fbhwc,
                                                 const float* __restrict__ prop,
                                                 const void* ihp, const void* iwp,
                                                 unsigned short* __restrict__ Apool) {
  int n = blockIdx.x;
  int tid = threadIdx.x;
  float sy = 14.f / scalar_f(ihp);
  float sx = 14.f / scalar_f(iwp);
  float bx1 = prop[n*4+0]*sx, by1 = prop[n*4+1]*sy;
  float bx2 = prop[n*4+2]*sx, by2 = prop[n*4+3]*sy;
  const float* fb = fbhwc + (size_t)(n >> 9) * 196 * 512;
  unsigned short* arow = Apool + (size_t)n * KTOT;
  int c4 = (tid & 127) << 2;
  int bh = tid >> 7;
  for (int b2i = 0; b2i < 49; b2i += 2) {
    int bin = b2i + bh;
    if (bin >= 49) continue;
    int py = bin / 7, px = bin - py * 7;
    float y = by1 + ((py + 0.5f) * (1.f/7.f)) * (by2 - by1) - 0.5f;
    float x = bx1 + ((px + 0.5f) * (1.f/7.f)) * (bx2 - bx1) - 0.5f;
    float y0f = floorf(y), x0f = floorf(x);
    float wy = y - y0f, wx = x - x0f;
    int y0  = min(max((int)y0f, 0), 13);
    int y1i = min(max((int)y0f + 1, 0), 13);
    int x0  = min(max((int)x0f, 0), 13);
    int x1i = min(max((int)x0f + 1, 0), 13);
    float w00 = (1.f - wy) * (1.f - wx), w01 = (1.f - wy) * wx;
    float w10 = wy * (1.f - wx),         w11 = wy * wx;
    const float4 f00 = *(const float4*)(fb + (y0 * 14 + x0 ) * 512 + c4);
    const float4 f01 = *(const float4*)(fb + (y0 * 14 + x1i) * 512 + c4);
    const float4 f10 = *(const float4*)(fb + (y1i * 14 + x0 ) * 512 + c4);
    const float4 f11 = *(const float4*)(fb + (y1i * 14 + x1i) * 512 + c4);
    float vx = f00.x*w00 + f01.x*w01 + f10.x*w10 + f11.x*w11;
    float vy = f00.y*w00 + f01.y*w01 + f10.y*w10 + f11.y*w11;
    float vz = f00.z*w00 + f01.z*w01 + f10.z*w10 + f11.z*w11;
    float vw = f00.w*w00 + f01.w*w01 + f10.w*w10 + f11.w*w11;
    unsigned lo = (unsigned)f2bf(vx) | ((unsigned)f2bf(vy) << 16);
    unsigned hi = (unsigned)f2bf(vz) | ((unsigned)f2bf(vw) << 16);
    *(uint2*)(arow + bin * 512 + c4) = make_uint2(lo, hi);
  }
}

__device__ __forceinline__ void gload16(const unsigned short* g, unsigned short* l) {
  __builtin_amdgcn_global_load_lds(
      (const __attribute__((address_space(1))) unsigned int*)g,
      (__attribute__((address_space(3))) unsigned int*)l, 16, 0, 0);
}

// ---- GEMM1: 256x256 tile, BK=32, 512 thr (8 waves), 4-deep LDS ring,
//      counted vmcnt (never drains in main loop), raw s_barrier, setprio.
//      Grid = 8(M) x 4(N) x 8(splitK) = 256 blocks = 1/CU. 128KB dynamic LDS.
__global__ __launch_bounds__(512, 2) void k_gemm1(
    const unsigned short* __restrict__ A,   // 2048 x 25088 bf16
    const unsigned short* __restrict__ B,   // 1024 x 25088 bf16
    unsigned short* __restrict__ hp)        // 8 x 2048 x 1024 bf16 partials
{
  extern __shared__ unsigned short lds[];   // [4][8192] A then [4][8192] B
  const int tid  = threadIdx.x;
  const int w    = tid >> 6;
  const int lane = tid & 63;
  const int wr = w >> 2, wc = w & 3;        // 2M x 4N waves
  // XCD swizzle (256 = 8*32): each XCD owns one K-split
  const int bid = (int)blockIdx.x;
  const int wg  = (bid & 7) * 32 + (bid >> 3);
  const int kb  = wg >> 5;
  const int gy  = (wg >> 2) & 7;
  const int gx  = wg & 3;

  f32x4 acc[8][4];
  const f32x4 zero = {0.f, 0.f, 0.f, 0.f};
#pragma unroll
  for (int m = 0; m < 8; ++m)
#pragma unroll
    for (int n = 0; n < 4; ++n) acc[m][n] = zero;

  // staging: 2 x 16B loads per matrix per thread per K-tile.
  // dst quad q at row r holds source quad q ^ ((r>>1)&3)  (both-sides swizzle)
  const int row0 = tid >> 2;                      // 0..127
  const int qdst = tid & 3;
  const int qsrc = qdst ^ ((tid >> 3) & 3);
  const int ldA0 = row0 * 32 + qdst * 8;          // ushort index in a buffer
  const int ldA1 = ldA0 + 4096;                   // rows 128..255
  const size_t kbase = (size_t)kb * 3136;
  const unsigned short* gA0 = A + (size_t)(gy * 256 + row0) * KTOT + kbase + qsrc * 8;
  const unsigned short* gA1 = gA0 + (size_t)128 * KTOT;
  const unsigned short* gB0 = B + (size_t)(gx * 256 + row0) * KTOT + kbase + qsrc * 8;
  const unsigned short* gB1 = gB0 + (size_t)128 * KTOT;

  // fragment read offsets (swizzle-matched); quad sel independent of m/n
  const int l15 = lane & 15;
  const int qsw = ((lane >> 4) ^ ((l15 >> 1) & 3)) * 8;
  int aoff[8], boff[4];
#pragma unroll
  for (int m = 0; m < 8; ++m) aoff[m] = (wr * 128 + m * 16 + l15) * 32 + qsw;
#pragma unroll
  for (int n = 0; n < 4; ++n) boff[n] = (wc * 64 + n * 16 + l15) * 32 + qsw;

  // prologue: fill ring with tiles 0..3 (16 loads outstanding)
#pragma unroll
  for (int t = 0; t < 4; ++t) {
    unsigned short* Ab = lds + t * 8192;
    unsigned short* Bb = lds + 32768 + t * 8192;
    gload16(gA0 + t * 32, Ab + ldA0);
    gload16(gA1 + t * 32, Ab + ldA1);
    gload16(gB0 + t * 32, Bb + ldA0);
    gload16(gB1 + t * 32, Bb + ldA1);
  }
  int cur = 0;

#define GTILE(VM, DOSTAGE, KNEXT) do {                                        \
    asm volatile("s_waitcnt vmcnt(" #VM ")" ::: "memory");                    \
    __builtin_amdgcn_s_barrier();                                             \
    const unsigned short* Ab = lds + cur * 8192;                              \
    const unsigned short* Bb = lds + 32768 + cur * 8192;                      \
    bf16x8 af[8], bfr[4];                                                     \
    _Pragma("unroll") for (int m = 0; m < 8; ++m)                             \
      af[m] = *reinterpret_cast<const bf16x8*>(Ab + aoff[m]);                 \
    _Pragma("unroll") for (int n = 0; n < 4; ++n)                             \
      bfr[n] = *reinterpret_cast<const bf16x8*>(Bb + boff[n]);                \
    asm volatile("s_waitcnt lgkmcnt(0)" ::: "memory");                        \
    __builtin_amdgcn_s_barrier();                                             \
    __builtin_amdgcn_sched_barrier(0);                                        \
    if (DOSTAGE) {                                                            \
      const size_t go = (size_t)(KNEXT) * 32;                                 \
      unsigned short* An = lds + cur * 8192;                                  \
      unsigned short* Bn = lds + 32768 + cur * 8192;                          \
      gload16(gA0 + go, An + ldA0);                                           \
      gload16(gA1 + go, An + ldA1);                                           \
      gload16(gB0 + go, Bn + ldA0);                                           \
      gload16(gB1 + go, Bn + ldA1);                                           \
    }                                                                         \
    __builtin_amdgcn_s_setprio(1);                                            \
    _Pragma("unroll") for (int m = 0; m < 8; ++m)                             \
      _Pragma("unroll") for (int n = 0; n < 4; ++n)                           \
        acc[m][n] = __builtin_amdgcn_mfma_f32_16x16x32_bf16(af[m], bfr[n],    \
                                                            acc[m][n], 0, 0, 0); \
    __builtin_amdgcn_s_setprio(0);                                            \
    cur = (cur + 1) & 3;                                                      \
  } while (0)

  // main: 94 iters, always 3 tiles in flight (vmcnt(12)); tail drains 12->8->4->0
  for (int kk = 0; kk < 94; ++kk) { GTILE(12, true, kk + 4); }
  GTILE(12, false, 0);
  GTILE(8,  false, 0);
  GTILE(4,  false, 0);
  GTILE(0,  false, 0);
#undef GTILE

  unsigned short* o = hp + (size_t)kb * (2048u * 1024u);
  const int r0 = gy * 256 + wr * 128 + ((lane >> 4) << 2);
  const int c0 = gx * 256 + wc * 64 + l15;
#pragma unroll
  for (int m = 0; m < 8; ++m)
#pragma unroll
    for (int n = 0; n < 4; ++n)
#pragma unroll
      for (int j = 0; j < 4; ++j)
        o[(size_t)(r0 + m * 16 + j) * 1024 + c0 + n * 16] = f2bf(acc[m][n][j]);
}

// ---- GEMM template (used for GEMM2 only): 128x128 tile, 2-phase dbuf
template<int OUTBF>
__global__ __launch_bounds__(256, 4) void k_gemm(
    const unsigned short* __restrict__ A,
    const unsigned short* __restrict__ B,
    void* __restrict__ outp,
    int Kst, int kIters, int nTileBits, int mTileBits, int ldc)
{
  __shared__ unsigned short As[2][4096];
  __shared__ unsigned short Bs[2][4096];
  const int tid  = threadIdx.x;
  const int w    = tid >> 6;
  const int lane = tid & 63;
  const int nwg = (int)gridDim.x, cpx = nwg >> 3;
  const int bid = (int)blockIdx.x;
  const int wg  = (bid & 7) * cpx + (bid >> 3);
  const int kb  = wg >> (mTileBits + nTileBits);
  const int rem = wg & ((1 << (mTileBits + nTileBits)) - 1);
  const int gy  = rem >> nTileBits;
  const int gx  = rem & ((1 << nTileBits) - 1);
  const int wr = w >> 1, wc = w & 1;

  f32x4 acc[4][4];
  const f32x4 zero = {0.f, 0.f, 0.f, 0.f};
#pragma unroll
  for (int m = 0; m < 4; ++m)
#pragma unroll
    for (int n = 0; n < 4; ++n) acc[m][n] = zero;

  const int r0   = 32 * w + (lane >> 2);
  const int qsrc = (lane & 3) ^ ((lane >> 3) & 3);
  const size_t kbase = (size_t)kb * kIters * 32;
  const unsigned short* gA = A + (size_t)(gy * 128 + r0) * Kst + kbase + qsrc * 8;
  const unsigned short* gB = B + (size_t)(gx * 128 + r0) * Kst + kbase + qsrc * 8;
  const int ldst = r0 * 32 + (lane & 3) * 8;

  const int swq = ((lane >> 4) ^ ((lane >> 1) & 3)) * 8;
  const int ar = (wr * 64 + (lane & 15)) * 32 + swq;
  const int br = (wc * 64 + (lane & 15)) * 32 + swq;

#define STAGE(bufi, it) do {                                         \
    const unsigned short* pa = gA + (size_t)(it) * 32;               \
    const unsigned short* pb = gB + (size_t)(it) * 32;               \
    gload16(pa,                      &As[bufi][ldst]);               \
    gload16(pa + (size_t)16 * Kst,   &As[bufi][ldst + 512]);         \
    gload16(pb,                      &Bs[bufi][ldst]);               \
    gload16(pb + (size_t)16 * Kst,   &Bs[bufi][ldst + 512]);         \
  } while (0)

  STAGE(0, 0);
  int cur = 0;
  for (int kk = 0; kk < kIters; ++kk) {
    __syncthreads();
    if (kk + 1 < kIters) STAGE(cur ^ 1, kk + 1);
    bf16x8 af[4], bfr[4];
#pragma unroll
    for (int m = 0; m < 4; ++m)
      af[m] = *reinterpret_cast<const bf16x8*>(&As[cur][ar + m * 512]);
#pragma unroll
    for (int n = 0; n < 4; ++n)
      bfr[n] = *reinterpret_cast<const bf16x8*>(&Bs[cur][br + n * 512]);
#pragma unroll
    for (int m = 0; m < 4; ++m)
#pragma unroll
      for (int n = 0; n < 4; ++n)
        acc[m][n] = __builtin_amdgcn_mfma_f32_16x16x32_bf16(af[m], bfr[n], acc[m][n], 0, 0, 0);
    cur ^= 1;
  }
#undef STAGE

  const size_t M = (size_t)(1 << mTileBits) * 128;
  const size_t splitStride = M * (size_t)ldc;
  const int r0o = gy * 128 + wr * 64 + ((lane >> 4) << 2);
  const int c0o = gx * 128 + wc * 64 + (lane & 15);
  if (OUTBF) {
    unsigned short* o = (unsigned short*)outp + (size_t)kb * splitStride;
#pragma unroll
    for (int m = 0; m < 4; ++m)
#pragma unroll
      for (int n = 0; n < 4; ++n)
#pragma unroll
        for (int j = 0; j < 4; ++j)
          o[(size_t)(r0o + m * 16 + j) * ldc + c0o + n * 16] = f2bf(acc[m][n][j]);
  } else {
    float* o = (float*)outp + (size_t)kb * splitStride;
#pragma unroll
    for (int m = 0; m < 4; ++m)
#pragma unroll
      for (int n = 0; n < 4; ++n)
#pragma unroll
        for (int j = 0; j < 4; ++j)
          o[(size_t)(r0o + m * 16 + j) * ldc + c0o + n * 16] = acc[m][n][j];
  }
}

// ---- combine 8 bf16 split-K partials + bias + ReLU -> hidden bf16
__global__ __launch_bounds__(256) void k_combine(const unsigned short* __restrict__ hp,
                                                 const float* __restrict__ b1,
                                                 unsigned short* __restrict__ hidden) {
  int gid = blockIdx.x * 256 + threadIdx.x;
  int id8 = gid * 8;
  int h = id8 & 1023;
  float a[8];
#pragma unroll
  for (int j = 0; j < 8; ++j) a[j] = b1[h + j];
#pragma unroll
  for (int s = 0; s < 8; ++s) {
    uint4 u = *(const uint4*)(hp + (size_t)s * 2097152 + id8);
    unsigned uu[4] = {u.x, u.y, u.z, u.w};
#pragma unroll
    for (int q = 0; q < 4; ++q) {
      union { unsigned u; float f; } lo, hi;
      lo.u = uu[q] << 16; hi.u = uu[q] & 0xFFFF0000u;
      a[2*q]   += lo.f;
      a[2*q+1] += hi.f;
    }
  }
  unsigned out[4];
#pragma unroll
  for (int q = 0; q < 4; ++q) {
    unsigned l  = f2bf(fmaxf(a[2*q],   0.f));
    unsigned hh = f2bf(fmaxf(a[2*q+1], 0.f));
    out[q] = l | (hh << 16);
  }
  *(uint4*)(hidden + id8) = make_uint4(out[0], out[1], out[2], out[3]);
}

// ---- W2 (1024x80 f32) -> W2T (128x1024 bf16, zero-padded)
__global__ __launch_bounds__(256) void k_w2t(const float* __restrict__ W2,
                                             unsigned short* __restrict__ W2T) {
  int id = blockIdx.x * 256 + threadIdx.x;
  int cls = id >> 10, k = id & 1023;
  float v = (cls < 80) ? W2[(size_t)k * 80 + cls] : 0.f;
  W2T[id] = f2bf(v);
}

// ---- BCE from gemm2 split-K partials
__global__ __launch_bounds__(256) void k_bce(const float* __restrict__ hp2,
                                             const float* __restrict__ b2,
                                             const float* __restrict__ gtc,
                                             const int* __restrict__ assign,
                                             float* __restrict__ per) {
  __shared__ float red[256];
  int t = threadIdx.x;
  int box = t >> 4, li = t & 15;
  int n = blockIdx.x * 16 + box;
  int lab = ((n >> 9) * 32 + assign[n]) * 80;
  float s = 0.f;
#pragma unroll
  for (int j = 0; j < 5; ++j) {
    int c = li + 16 * j;
    size_t o = (size_t)n * 128 + c;
    float x = hp2[o] + hp2[o + 262144] + hp2[o + 524288] + hp2[o + 786432] + b2[c];
    float y = gtc[lab + c];
    float ce = log1pf(expf(-fabsf(x)));
    s += y * (fmaxf(-x, 0.f) + ce) + (1.f - y) * (fmaxf(x, 0.f) + ce);
  }
  red[t] = s;
  __syncthreads();
  if (li == 0) {
    float tot = 0.f;
#pragma unroll
    for (int i = 0; i < 16; ++i) tot += red[box * 16 + i];
    per[n] = tot * (1.f / 80.f);
  }
}

// ---- fg-masked per-batch mean
__global__ __launch_bounds__(512) void k_reduce(const float* __restrict__ per,
                                                const float* __restrict__ max_iou,
                                                const int* __restrict__ flag,
                                                float* __restrict__ out) {
  __shared__ float sv[8], sf[8];
  int b = blockIdx.x, tid = threadIdx.x;
  float thr = (*flag) ? 0.85f : 0.5f;
  int n = b * 512 + tid;
  float f = (max_iou[n] >= thr) ? 1.f : 0.f;
  float v = per[n] * f;
#pragma unroll
  for (int o = 32; o > 0; o >>= 1) {
    v += __shfl_down(v, o);
    f += __shfl_down(f, o);
  }
  int wv = tid >> 6;
  if ((tid & 63) == 0) { sv[wv] = v; sf[wv] = f; }
  __syncthreads();
  if (tid == 0) {
    float S = 0.f, F = 0.f;
#pragma unroll
    for (int i = 0; i < 8; ++i) { S += sv[i]; F += sf[i]; }
    out[b] = (F > 0.f) ? S / fmaxf(F, 1.f) : 0.f;
  }
}

extern "C" void kernel_launch(void* const* d_in, const int* in_sizes, int n_in,
                              void* d_out, int out_size, void* d_ws, size_t ws_size,
                              hipStream_t stream) {
  const float* feature = (const float*)d_in[0];
  const float* prop    = (const float*)d_in[1];
  const float* gtb     = (const float*)d_in[2];
  const float* gtc     = (const float*)d_in[3];
  const float* W1      = (const float*)d_in[4];
  const float* b1      = (const float*)d_in[5];
  const float* W2      = (const float*)d_in[6];
  const float* b2      = (const float*)d_in[7];
  const void*  ihp     = d_in[8];
  const void*  iwp     = d_in[9];

  char* ws = (char*)d_ws;
  float*          fbhwc  = (float*)(ws);
  unsigned short* W1T    = (unsigned short*)(ws + 1605632);
  unsigned short* Apool  = (unsigned short*)(ws + 52985856);
  unsigned short* hp     = (unsigned short*)(ws + 155746304);
  float*          max_iou= (float*)(ws + 189300736);
  int*            assign = (int*)(ws + 189308928);
  float*          per    = (float*)(ws + 189317120);
  int*            flag   = (int*)(ws + 189325312);
  unsigned short* hidden = W1T;
  unsigned short* W2T    = Apool;
  float*          hp2    = (float*)((char*)Apool + 262144);

  hipFuncSetAttribute((const void*)k_gemm1,
                      hipFuncAttributeMaxDynamicSharedMemorySize, 131072);

  hipMemsetAsync(flag, 0, sizeof(int), stream);
  k_meant  <<<1568, 256, 0, stream>>>(feature, fbhwc);
  k_iou    <<<8, 256, 0, stream>>>(prop, gtb, max_iou, assign, flag);
  k_w1t    <<<dim3(392, 16), 256, 0, stream>>>(W1, W1T);
  k_roipool<<<2048, 256, 0, stream>>>(fbhwc, prop, ihp, iwp, Apool);
  // GEMM1: 256x256 tiles, split-K=8 -> 256 blocks, 128KB dynamic LDS
  k_gemm1  <<<256, 512, 131072, stream>>>(Apool, W1T, hp);
  k_combine<<<1024, 256, 0, stream>>>(hp, b1, hidden);
  k_w2t    <<<512, 256, 0, stream>>>(W2, W2T);
  // GEMM2: M=2048, N=128, K=1024, split-K=4
  k_gemm<0><<<64, 256, 0, stream>>>(hidden, W2T, hp2, 1024, 8, 0, 4, 128);
  k_bce    <<<128, 256, 0, stream>>>(hp2, b2, gtc, assign, per);
  k_reduce <<<4, 512, 0, stream>>>(per, max_iou, flag, (float*)d_out);
}

// Round 5
// 196.906 us; speedup vs baseline: 1.6322x; 1.0313x over previous
//
#include <hip/hip_runtime.h>
#include <cstdint>
#include <cstddef>

#define KTOT 25088   // C*P*P = 512*49 (K-permuted: k' = bin*512 + c)
#define NBOX 2048
#define HID  1024

typedef __bf16 bf16x8 __attribute__((ext_vector_type(8)));
typedef float  f32x4  __attribute__((ext_vector_type(4)));

__device__ __forceinline__ unsigned short f2bf(float f) {
  union { float f; unsigned u; } v; v.f = f;
  unsigned r = v.u + 0x7FFFu + ((v.u >> 16) & 1u);   // RNE
  return (unsigned short)(r >> 16);
}

__device__ __forceinline__ float scalar_f(const void* p) {
  int iv = *(const int*)p;
  if (iv > 0 && iv < (1 << 20)) return (float)iv;
  return *(const float*)p;
}

// ---- kernel 1: mean over T + transpose -> fbhwc (B,14,14,C) f32
__global__ __launch_bounds__(256) void k_meant(const float* __restrict__ feature,
                                               float* __restrict__ fbhwc) {
  int id = blockIdx.x * 256 + threadIdx.x;
  if (id >= 4 * 512 * 196) return;
  int pix = id % 196;
  int c   = (id / 196) & 511;
  int b   = id / (196 * 512);
  const float* p = feature + ((size_t)(b * 512 + c) * 8) * 196 + pix;
  float s = 0.f;
#pragma unroll
  for (int t = 0; t < 8; ++t) s += p[t * 196];
  fbhwc[((size_t)(b * 196 + pix)) * 512 + c] = s * 0.125f;
}

// ---- kernel 2: IoU max/argmax + any_fg flag
__global__ __launch_bounds__(256) void k_iou(const float* __restrict__ prop,
                                             const float* __restrict__ gtb,
                                             float* __restrict__ max_iou,
                                             int* __restrict__ assign,
                                             int* __restrict__ flag) {
  __shared__ float g[128];
  int gid = blockIdx.x * 256 + threadIdx.x;
  int b = gid >> 9;
  if (threadIdx.x < 128) g[threadIdx.x] = gtb[b * 128 + threadIdx.x];
  __syncthreads();
  float x1 = prop[gid * 4 + 0], y1 = prop[gid * 4 + 1];
  float x2 = prop[gid * 4 + 2], y2 = prop[gid * 4 + 3];
  float aa = (x2 - x1) * (y2 - y1);
  float best = -1e30f; int arg = 0;
  for (int m = 0; m < 32; ++m) {
    float gx1 = g[m*4], gy1 = g[m*4+1], gx2 = g[m*4+2], gy2 = g[m*4+3];
    float iw = fmaxf(fminf(x2, gx2) - fmaxf(x1, gx1), 0.f);
    float ih = fmaxf(fminf(y2, gy2) - fmaxf(y1, gy1), 0.f);
    float inter = iw * ih;
    float ab = (gx2 - gx1) * (gy2 - gy1);
    float iou = inter / (aa + ab - inter + 1e-8f);
    if (iou > best) { best = iou; arg = m; }
  }
  max_iou[gid] = best; assign[gid] = arg;
  if (best >= 0.85f) atomicOr(flag, 1);
}

// ---- kernel 3: W1 -> W1T (1024 x 25088 bf16), col k'=bin*512+c. 64x64 tiles.
__global__ __launch_bounds__(256) void k_w1t(const float* __restrict__ W1,
                                             unsigned short* __restrict__ W1T) {
  __shared__ unsigned short tile[64][68];
  int kp0 = blockIdx.x * 64;
  int h0  = blockIdx.y * 64;
  int t = threadIdx.x;
  int seg = t & 15, ro = t >> 4;
#pragma unroll
  for (int r = 0; r < 4; ++r) {
    int i = ro + r * 16;
    int kp = kp0 + i;
    int srow = (kp & 511) * 49 + (kp >> 9);
    float4 v = *(const float4*)(W1 + (size_t)srow * 1024 + h0 + seg * 4);
    tile[i][seg*4+0] = f2bf(v.x);
    tile[i][seg*4+1] = f2bf(v.y);
    tile[i][seg*4+2] = f2bf(v.z);
    tile[i][seg*4+3] = f2bf(v.w);
  }
  __syncthreads();
#pragma unroll
  for (int r = 0; r < 4; ++r) {
    int hi = ro + r * 16;
    unsigned a = tile[seg*4+0][hi];
    unsigned b = tile[seg*4+1][hi];
    unsigned c = tile[seg*4+2][hi];
    unsigned d = tile[seg*4+3][hi];
    *(uint2*)(W1T + (size_t)(h0+hi)*KTOT + kp0 + seg*4) =
        make_uint2(a | (b << 16), c | (d << 16));
  }
}

// ---- kernel 4: ROI-pool, vectorized
__global__ __launch_bounds__(256) void k_roipool(const float* __restrict__ fbhwc,
                                                 const float* __restrict__ prop,
                                                 const void* ihp, const void* iwp,
                                                 unsigned short* __restrict__ Apool) {
  int n = blockIdx.x;
  int tid = threadIdx.x;
  float sy = 14.f / scalar_f(ihp);
  float sx = 14.f / scalar_f(iwp);
  float bx1 = prop[n*4+0]*sx, by1 = prop[n*4+1]*sy;
  float bx2 = prop[n*4+2]*sx, by2 = prop[n*4+3]*sy;
  const float* fb = fbhwc + (size_t)(n >> 9) * 196 * 512;
  unsigned short* arow = Apool + (size_t)n * KTOT;
  int c4 = (tid & 127) << 2;
  int bh = tid >> 7;
  for (int b2i = 0; b2i < 49; b2i += 2) {
    int bin = b2i + bh;
    if (bin >= 49) continue;
    int py = bin / 7, px = bin - py * 7;
    float y = by1 + ((py + 0.5f) * (1.f/7.f)) * (by2 - by1) - 0.5f;
    float x = bx1 + ((px + 0.5f) * (1.f/7.f)) * (bx2 - bx1) - 0.5f;
    float y0f = floorf(y), x0f = floorf(x);
    float wy = y - y0f, wx = x - x0f;
    int y0  = min(max((int)y0f, 0), 13);
    int y1i = min(max((int)y0f + 1, 0), 13);
    int x0  = min(max((int)x0f, 0), 13);
    int x1i = min(max((int)x0f + 1, 0), 13);
    float w00 = (1.f - wy) * (1.f - wx), w01 = (1.f - wy) * wx;
    float w10 = wy * (1.f - wx),         w11 = wy * wx;
    const float4 f00 = *(const float4*)(fb + (y0 * 14 + x0 ) * 512 + c4);
    const float4 f01 = *(const float4*)(fb + (y0 * 14 + x1i) * 512 + c4);
    const float4 f10 = *(const float4*)(fb + (y1i * 14 + x0 ) * 512 + c4);
    const float4 f11 = *(const float4*)(fb + (y1i * 14 + x1i) * 512 + c4);
    float vx = f00.x*w00 + f01.x*w01 + f10.x*w10 + f11.x*w11;
    float vy = f00.y*w00 + f01.y*w01 + f10.y*w10 + f11.y*w11;
    float vz = f00.z*w00 + f01.z*w01 + f10.z*w10 + f11.z*w11;
    float vw = f00.w*w00 + f01.w*w01 + f10.w*w10 + f11.w*w11;
    unsigned lo = (unsigned)f2bf(vx) | ((unsigned)f2bf(vy) << 16);
    unsigned hi = (unsigned)f2bf(vz) | ((unsigned)f2bf(vw) << 16);
    *(uint2*)(arow + bin * 512 + c4) = make_uint2(lo, hi);
  }
}

__device__ __forceinline__ void gload16(const unsigned short* g, unsigned short* l) {
  __builtin_amdgcn_global_load_lds(
      (const __attribute__((address_space(1))) unsigned int*)g,
      (__attribute__((address_space(3))) unsigned int*)l, 16, 0, 0);
}

// ---- GEMM1: 256x256 tile, BK=64, 512 thr (8 waves, 2Mx4N), dbuf LDS,
//      m201-style 4-phase schedule: per phase {dsr frag || stage 1 K-sliced
//      unit -> barrier -> lgkm(0) -> 16 MFMA -> barrier}, vmcnt(2) counted.
//      Units per K-step: AK0/AK1/BK0/BK1 (16KB each), staged 1 per phase.
__global__ __launch_bounds__(512, 2) void k_gemm1(
    const unsigned short* __restrict__ A,   // 2048 x 25088 bf16
    const unsigned short* __restrict__ B,   // 1024 x 25088 bf16
    unsigned short* __restrict__ hp)        // 8 x 2048 x 1024 bf16 partials
{
  extern __shared__ unsigned short lds[];   // 2 bufs x 32768: [AK0|AK1|BK0|BK1]
  const int tid  = threadIdx.x;
  const int w    = tid >> 6;
  const int lane = tid & 63;
  const int l15  = lane & 15;
  const int wr = w >> 2, wc = w & 3;        // 2M x 4N waves
  // XCD swizzle: 256 = 8 XCDs x 32; each XCD owns one K-split
  const int bid = (int)blockIdx.x;
  const int wg  = (bid & 7) * 32 + (bid >> 3);
  const int kb  = wg >> 5;
  const int gy  = (wg >> 2) & 7;
  const int gx  = wg & 3;

  f32x4 acc[8][4];
  const f32x4 zero = {0.f, 0.f, 0.f, 0.f};
#pragma unroll
  for (int m = 0; m < 8; ++m)
#pragma unroll
    for (int n = 0; n < 4; ++n) acc[m][n] = zero;

  // --- staging constants. Unit layout (16KB = 256 rows x 32 K bf16):
  // logical (r, q[0..4)) -> phys ushort off = (r>>1)*64 + p*8,
  //   p = (q | ((r&1)<<2)) ^ ((r>>1)&7)   (per-128B-line 16B-slot permute)
  // thread t, round rr stages phys 16B-unit d = rr*512+t  (linear dst).
  const int xsw  = (tid & 7) ^ ((tid >> 3) & 7);
  const int rloc = ((tid >> 3) << 1) + (xsw >> 2);
  const int qsrc = xsw & 3;
  const size_t kbase = (size_t)kb * 3136;
  const unsigned short* gAp = A + (size_t)(gy * 256 + rloc) * KTOT + kbase + qsrc * 8;
  const unsigned short* gBp = B + (size_t)(gx * 256 + rloc) * KTOT + kbase + qsrc * 8;
  const int dstc = tid * 8;

  // --- fragment read constants (swizzle-matched)
  const int pfr   = ((lane >> 4) | ((l15 & 1) << 2)) ^ (l15 >> 1);
  const int aoffc = wr * 4096 + (l15 >> 1) * 64 + pfr * 8;   // + m*512 + unit
  const int boffc = wc * 2048 + (l15 >> 1) * 64 + pfr * 8;   // + n*512 + unit

  bf16x8 af[8], b0[2], b1[2];

#define VMW2 asm volatile("s_waitcnt vmcnt(2)" ::: "memory");
#define VMW0 asm volatile("s_waitcnt vmcnt(0)" ::: "memory");
#define DSR_A(CB, UOFF) _Pragma("unroll") for (int m = 0; m < 8; ++m) \
    af[m] = *reinterpret_cast<const bf16x8*>(lds + (CB) + (UOFF) + aoffc + m * 512);
#define DSR_B(BV, CB, UOFF, NH) _Pragma("unroll") for (int nn = 0; nn < 2; ++nn) \
    BV[nn] = *reinterpret_cast<const bf16x8*>(lds + (CB) + (UOFF) + boffc + ((NH)*2+nn) * 512);
#define MM16(BV, NH) _Pragma("unroll") for (int m = 0; m < 8; ++m) \
    _Pragma("unroll") for (int nn = 0; nn < 2; ++nn) \
      acc[m][(NH)*2+nn] = __builtin_amdgcn_mfma_f32_16x16x32_bf16(af[m], BV[nn], acc[m][(NH)*2+nn], 0, 0, 0);
#define STG(OB, UOFF, GP, KOFF) { \
    gload16((GP) + (KOFF),                      lds + (OB) + (UOFF) + dstc); \
    gload16((GP) + (KOFF) + (size_t)128 * KTOT, lds + (OB) + (UOFF) + 4096 + dstc); }
#define PHTAIL \
    __builtin_amdgcn_sched_barrier(0); \
    __builtin_amdgcn_s_barrier(); \
    asm volatile("s_waitcnt lgkmcnt(0)" ::: "memory"); \
    __builtin_amdgcn_sched_barrier(0); \
    __builtin_amdgcn_s_setprio(1);
#define PHEND \
    __builtin_amdgcn_s_setprio(0); \
    __builtin_amdgcn_s_barrier();

  // KSTEP: compute buf CB; stage step's units for next step into buf OB at KN.
#define KSTEP(CB, OB, KN, DOST, VM1C)                                          \
  { /* ph0: frags(AK0,BK0-nh0); stage AK0' */                                  \
    DSR_A(CB, 0)                                                               \
    DSR_B(b0, CB, 16384, 0)                                                    \
    if (DOST) STG(OB, 0, gAp, KN)                                              \
    PHTAIL  MM16(b0, 0)  PHEND                                                 \
    /* ph1: frags(BK0-nh1); stage BK0' */                                      \
    VM1C                                                                       \
    DSR_B(b1, CB, 16384, 1)                                                    \
    if (DOST) STG(OB, 16384, gBp, KN)                                          \
    PHTAIL  MM16(b1, 1)  PHEND                                                 \
    /* ph2: frags(AK1,BK1-nh0); stage AK1' */                                  \
    DSR_A(CB, 8192)                                                            \
    DSR_B(b0, CB, 24576, 0)                                                    \
    if (DOST) STG(OB, 8192, gAp, (KN) + 32)                                    \
    PHTAIL  MM16(b0, 0)  PHEND                                                 \
    /* ph3: frags(BK1-nh1); stage BK1' */                                      \
    if (DOST) VMW2                                                             \
    DSR_B(b1, CB, 24576, 1)                                                    \
    if (DOST) STG(OB, 24576, gBp, (KN) + 32)                                   \
    PHTAIL  MM16(b1, 1)  PHEND                                                 \
  }

  // prologue: stage step 0's 4 units into buf0 (order AK0,BK0,AK1,BK1)
  STG(0, 0,     gAp, 0)
  STG(0, 16384, gBp, 0)
  STG(0, 8192,  gAp, 32)
  STG(0, 24576, gBp, 32)
  asm volatile("s_waitcnt vmcnt(4)" ::: "memory");
  __builtin_amdgcn_s_barrier();

#pragma unroll 1
  for (int s = 0; s < 48; s += 2) {
    const int kn1 = (s + 1) * 64;
    const int kn2 = (s + 2) * 64;
    KSTEP(0,     32768, kn1, true, VMW2)   // even step: compute buf0, stage buf1
    KSTEP(32768, 0,     kn2, true, VMW2)   // odd step:  compute buf1, stage buf0
  }
  // final step 48 (buf0), no staging; ph1 drains remaining AK1,BK1
  KSTEP(0, 32768, 0, false, VMW0)

#undef KSTEP
#undef PHEND
#undef PHTAIL
#undef STG
#undef MM16
#undef DSR_B
#undef DSR_A
#undef VMW0
#undef VMW2

  unsigned short* o = hp + (size_t)kb * (2048u * 1024u);
  const int r0 = gy * 256 + wr * 128 + ((lane >> 4) << 2);
  const int c0 = gx * 256 + wc * 64 + l15;
#pragma unroll
  for (int m = 0; m < 8; ++m)
#pragma unroll
    for (int n = 0; n < 4; ++n)
#pragma unroll
      for (int j = 0; j < 4; ++j)
        o[(size_t)(r0 + m * 16 + j) * 1024 + c0 + n * 16] = f2bf(acc[m][n][j]);
}

// ---- GEMM template (GEMM2 only): 128x128 tile, 2-phase dbuf
template<int OUTBF>
__global__ __launch_bounds__(256, 4) void k_gemm(
    const unsigned short* __restrict__ A,
    const unsigned short* __restrict__ B,
    void* __restrict__ outp,
    int Kst, int kIters, int nTileBits, int mTileBits, int ldc)
{
  __shared__ unsigned short As[2][4096];
  __shared__ unsigned short Bs[2][4096];
  const int tid  = threadIdx.x;
  const int w    = tid >> 6;
  const int lane = tid & 63;
  const int nwg = (int)gridDim.x, cpx = nwg >> 3;
  const int bid = (int)blockIdx.x;
  const int wg  = (bid & 7) * cpx + (bid >> 3);
  const int kb  = wg >> (mTileBits + nTileBits);
  const int rem = wg & ((1 << (mTileBits + nTileBits)) - 1);
  const int gy  = rem >> nTileBits;
  const int gx  = rem & ((1 << nTileBits) - 1);
  const int wr = w >> 1, wc = w & 1;

  f32x4 acc[4][4];
  const f32x4 zero = {0.f, 0.f, 0.f, 0.f};
#pragma unroll
  for (int m = 0; m < 4; ++m)
#pragma unroll
    for (int n = 0; n < 4; ++n) acc[m][n] = zero;

  const int r0   = 32 * w + (lane >> 2);
  const int qsrc = (lane & 3) ^ ((lane >> 3) & 3);
  const size_t kbase = (size_t)kb * kIters * 32;
  const unsigned short* gA = A + (size_t)(gy * 128 + r0) * Kst + kbase + qsrc * 8;
  const unsigned short* gB = B + (size_t)(gx * 128 + r0) * Kst + kbase + qsrc * 8;
  const int ldst = r0 * 32 + (lane & 3) * 8;

  const int swq = ((lane >> 4) ^ ((lane >> 1) & 3)) * 8;
  const int ar = (wr * 64 + (lane & 15)) * 32 + swq;
  const int br = (wc * 64 + (lane & 15)) * 32 + swq;

#define STAGE(bufi, it) do {                                         \
    const unsigned short* pa = gA + (size_t)(it) * 32;               \
    const unsigned short* pb = gB + (size_t)(it) * 32;               \
    gload16(pa,                      &As[bufi][ldst]);               \
    gload16(pa + (size_t)16 * Kst,   &As[bufi][ldst + 512]);         \
    gload16(pb,                      &Bs[bufi][ldst]);               \
    gload16(pb + (size_t)16 * Kst,   &Bs[bufi][ldst + 512]);         \
  } while (0)

  STAGE(0, 0);
  int cur = 0;
  for (int kk = 0; kk < kIters; ++kk) {
    __syncthreads();
    if (kk + 1 < kIters) STAGE(cur ^ 1, kk + 1);
    bf16x8 af[4], bfr[4];
#pragma unroll
    for (int m = 0; m < 4; ++m)
      af[m] = *reinterpret_cast<const bf16x8*>(&As[cur][ar + m * 512]);
#pragma unroll
    for (int n = 0; n < 4; ++n)
      bfr[n] = *reinterpret_cast<const bf16x8*>(&Bs[cur][br + n * 512]);
#pragma unroll
    for (int m = 0; m < 4; ++m)
#pragma unroll
      for (int n = 0; n < 4; ++n)
        acc[m][n] = __builtin_amdgcn_mfma_f32_16x16x32_bf16(af[m], bfr[n], acc[m][n], 0, 0, 0);
    cur ^= 1;
  }
#undef STAGE

  const size_t M = (size_t)(1 << mTileBits) * 128;
  const size_t splitStride = M * (size_t)ldc;
  const int r0o = gy * 128 + wr * 64 + ((lane >> 4) << 2);
  const int c0o = gx * 128 + wc * 64 + (lane & 15);
  if (OUTBF) {
    unsigned short* o = (unsigned short*)outp + (size_t)kb * splitStride;
#pragma unroll
    for (int m = 0; m < 4; ++m)
#pragma unroll
      for (int n = 0; n < 4; ++n)
#pragma unroll
        for (int j = 0; j < 4; ++j)
          o[(size_t)(r0o + m * 16 + j) * ldc + c0o + n * 16] = f2bf(acc[m][n][j]);
  } else {
    float* o = (float*)outp + (size_t)kb * splitStride;
#pragma unroll
    for (int m = 0; m < 4; ++m)
#pragma unroll
      for (int n = 0; n < 4; ++n)
#pragma unroll
        for (int j = 0; j < 4; ++j)
          o[(size_t)(r0o + m * 16 + j) * ldc + c0o + n * 16] = acc[m][n][j];
  }
}

// ---- combine 8 bf16 split-K partials + bias + ReLU -> hidden bf16
__global__ __launch_bounds__(256) void k_combine(const unsigned short* __restrict__ hp,
                                                 const float* __restrict__ b1,
                                                 unsigned short* __restrict__ hidden) {
  int gid = blockIdx.x * 256 + threadIdx.x;
  int id8 = gid * 8;
  int h = id8 & 1023;
  float a[8];
#pragma unroll
  for (int j = 0; j < 8; ++j) a[j] = b1[h + j];
#pragma unroll
  for (int s = 0; s < 8; ++s) {
    uint4 u = *(const uint4*)(hp + (size_t)s * 2097152 + id8);
    unsigned uu[4] = {u.x, u.y, u.z, u.w};
#pragma unroll
    for (int q = 0; q < 4; ++q) {
      union { unsigned u; float f; } lo, hi;
      lo.u = uu[q] << 16; hi.u = uu[q] & 0xFFFF0000u;
      a[2*q]   += lo.f;
      a[2*q+1] += hi.f;
    }
  }
  unsigned out[4];
#pragma unroll
  for (int q = 0; q < 4; ++q) {
    unsigned l  = f2bf(fmaxf(a[2*q],   0.f));
    unsigned hh = f2bf(fmaxf(a[2*q+1], 0.f));
    out[q] = l | (hh << 16);
  }
  *(uint4*)(hidden + id8) = make_uint4(out[0], out[1], out[2], out[3]);
}

// ---- W2 (1024x80 f32) -> W2T (128x1024 bf16, zero-padded)
__global__ __launch_bounds__(256) void k_w2t(const float* __restrict__ W2,
                                             unsigned short* __restrict__ W2T) {
  int id = blockIdx.x * 256 + threadIdx.x;
  int cls = id >> 10, k = id & 1023;
  float v = (cls < 80) ? W2[(size_t)k * 80 + cls] : 0.f;
  W2T[id] = f2bf(v);
}

// ---- BCE from gemm2 split-K partials
__global__ __launch_bounds__(256) void k_bce(const float* __restrict__ hp2,
                                             const float* __restrict__ b2,
                                             const float* __restrict__ gtc,
                                             const int* __restrict__ assign,
                                             float* __restrict__ per) {
  __shared__ float red[256];
  int t = threadIdx.x;
  int box = t >> 4, li = t & 15;
  int n = blockIdx.x * 16 + box;
  int lab = ((n >> 9) * 32 + assign[n]) * 80;
  float s = 0.f;
#pragma unroll
  for (int j = 0; j < 5; ++j) {
    int c = li + 16 * j;
    size_t o = (size_t)n * 128 + c;
    float x = hp2[o] + hp2[o + 262144] + hp2[o + 524288] + hp2[o + 786432] + b2[c];
    float y = gtc[lab + c];
    float ce = log1pf(expf(-fabsf(x)));
    s += y * (fmaxf(-x, 0.f) + ce) + (1.f - y) * (fmaxf(x, 0.f) + ce);
  }
  red[t] = s;
  __syncthreads();
  if (li == 0) {
    float tot = 0.f;
#pragma unroll
    for (int i = 0; i < 16; ++i) tot += red[box * 16 + i];
    per[n] = tot * (1.f / 80.f);
  }
}

// ---- fg-masked per-batch mean
__global__ __launch_bounds__(512) void k_reduce(const float* __restrict__ per,
                                                const float* __restrict__ max_iou,
                                                const int* __restrict__ flag,
                                                float* __restrict__ out) {
  __shared__ float sv[8], sf[8];
  int b = blockIdx.x, tid = threadIdx.x;
  float thr = (*flag) ? 0.85f : 0.5f;
  int n = b * 512 + tid;
  float f = (max_iou[n] >= thr) ? 1.f : 0.f;
  float v = per[n] * f;
#pragma unroll
  for (int o = 32; o > 0; o >>= 1) {
    v += __shfl_down(v, o);
    f += __shfl_down(f, o);
  }
  int wv = tid >> 6;
  if ((tid & 63) == 0) { sv[wv] = v; sf[wv] = f; }
  __syncthreads();
  if (tid == 0) {
    float S = 0.f, F = 0.f;
#pragma unroll
    for (int i = 0; i < 8; ++i) { S += sv[i]; F += sf[i]; }
    out[b] = (F > 0.f) ? S / fmaxf(F, 1.f) : 0.f;
  }
}

extern "C" void kernel_launch(void* const* d_in, const int* in_sizes, int n_in,
                              void* d_out, int out_size, void* d_ws, size_t ws_size,
                              hipStream_t stream) {
  const float* feature = (const float*)d_in[0];
  const float* prop    = (const float*)d_in[1];
  const float* gtb     = (const float*)d_in[2];
  const float* gtc     = (const float*)d_in[3];
  const float* W1      = (const float*)d_in[4];
  const float* b1      = (const float*)d_in[5];
  const float* W2      = (const float*)d_in[6];
  const float* b2      = (const float*)d_in[7];
  const void*  ihp     = d_in[8];
  const void*  iwp     = d_in[9];

  char* ws = (char*)d_ws;
  float*          fbhwc  = (float*)(ws);
  unsigned short* W1T    = (unsigned short*)(ws + 1605632);
  unsigned short* Apool  = (unsigned short*)(ws + 52985856);
  unsigned short* hp     = (unsigned short*)(ws + 155746304);
  float*          max_iou= (float*)(ws + 189300736);
  int*            assign = (int*)(ws + 189308928);
  float*          per    = (float*)(ws + 189317120);
  int*            flag   = (int*)(ws + 189325312);
  unsigned short* hidden = W1T;
  unsigned short* W2T    = Apool;
  float*          hp2    = (float*)((char*)Apool + 262144);

  hipFuncSetAttribute((const void*)k_gemm1,
                      hipFuncAttributeMaxDynamicSharedMemorySize, 131072);

  hipMemsetAsync(flag, 0, sizeof(int), stream);
  k_meant  <<<1568, 256, 0, stream>>>(feature, fbhwc);
  k_iou    <<<8, 256, 0, stream>>>(prop, gtb, max_iou, assign, flag);
  k_w1t    <<<dim3(392, 16), 256, 0, stream>>>(W1, W1T);
  k_roipool<<<2048, 256, 0, stream>>>(fbhwc, prop, ihp, iwp, Apool);
  // GEMM1: 256x256 tiles, split-K=8 -> 256 blocks, 128KB dynamic LDS
  k_gemm1  <<<256, 512, 131072, stream>>>(Apool, W1T, hp);
  k_combine<<<1024, 256, 0, stream>>>(hp, b1, hidden);
  k_w2t    <<<512, 256, 0, stream>>>(W2, W2T);
  // GEMM2: M=2048, N=128, K=1024, split-K=4
  k_gemm<0><<<64, 256, 0, stream>>>(hidden, W2T, hp2, 1024, 8, 0, 4, 128);
  k_bce    <<<128, 256, 0, stream>>>(hp2, b2, gtc, assign, per);
  k_reduce <<<4, 512, 0, stream>>>(per, max_iou, flag, (float*)d_out);
}